// Round 5
// baseline (83.846 us; speedup 1.0000x reference)
//
#include <hip/hip_runtime.h>

typedef _Float16 half8 __attribute__((ext_vector_type(8)));
typedef __fp16   fp16x2 __attribute__((ext_vector_type(2)));
typedef float    f32x4 __attribute__((ext_vector_type(4)));

#define DEV static __device__ __forceinline__

DEV unsigned short f2h(float f) {
  _Float16 h = (_Float16)f;
  return __builtin_bit_cast(unsigned short, h);
}
DEV float lrelu(float x) { return x > 0.f ? x : 0.01f * x; }
DEV f32x4 mfma16(half8 a, half8 b, f32x4 c) {
  return __builtin_amdgcn_mfma_f32_16x16x32_f16(a, b, c, 0, 0, 0);
}
DEV half8 cvt8(float4 lo, float4 hi) {
  struct { fp16x2 a, b, c, d; } t;
  t.a = __builtin_amdgcn_cvt_pkrtz(lo.x, lo.y);
  t.b = __builtin_amdgcn_cvt_pkrtz(lo.z, lo.w);
  t.c = __builtin_amdgcn_cvt_pkrtz(hi.x, hi.y);
  t.d = __builtin_amdgcn_cvt_pkrtz(hi.z, hi.w);
  return __builtin_bit_cast(half8, t);
}

// dims: B=4 N=256 H=768 D=200 NH=5 HD=40 OUT=12
// padded K: head 320 (5*64), tail/P 224. Inputs f32, output f32.
// No LDS anywhere: all MFMA fragments load direct from global (L2/L3-hot).

// ================= K1: gemm1 wave-tiles (bid<28) + prep items =================
__global__ void __launch_bounds__(256) k1(
    const float* __restrict__ wr, const float* __restrict__ hw,
    const float* __restrict__ tw, const float* __restrict__ hb,
    const float* __restrict__ tb, const float* __restrict__ U,
    const float* __restrict__ W, const float* __restrict__ dw,
    unsigned short* __restrict__ headp, unsigned short* __restrict__ tail16,
    unsigned short* __restrict__ P16, unsigned short* __restrict__ DWhp,
    unsigned short* __restrict__ DWtp, float* __restrict__ biasH,
    float* __restrict__ biasT, float* __restrict__ DWs,
    unsigned short* __restrict__ Gp)
{
  int bid = blockIdx.x;
  if (bid < 28) {
    // ---- GEMM1: out[1024 x 400] = wr[1024x768] x [hw;tw][400x768]^T, leaky_relu
    int w = bid * 4 + (threadIdx.x >> 6);           // wave-tile id 0..111
    int lane = threadIdx.x & 63, r15 = lane & 15, g8 = lane >> 4;
    int mt = w / 7, nt = w % 7;
    int rb = mt * 64, cb = nt * 64;

    const float4* aptr[4];
    #pragma unroll
    for (int g = 0; g < 4; ++g)
      aptr[g] = reinterpret_cast<const float4*>(wr + (rb + g * 16 + r15) * 768);
    const float4* bptr[4];
    #pragma unroll
    for (int h = 0; h < 4; ++h) {
      int c = cb + h * 16 + r15;
      int cl = c < 399 ? c : 399;
      bptr[h] = reinterpret_cast<const float4*>(
          (cl < 200) ? hw + cl * 768 : tw + (cl - 200) * 768);
    }

    f32x4 acc[4][4] = {};
    for (int kt = 0; kt < 24; ++kt) {
      int idx = kt * 8 + g8 * 2;
      half8 a[4], bb[4];
      #pragma unroll
      for (int g = 0; g < 4; ++g) a[g] = cvt8(aptr[g][idx], aptr[g][idx + 1]);
      #pragma unroll
      for (int h = 0; h < 4; ++h) bb[h] = cvt8(bptr[h][idx], bptr[h][idx + 1]);
      #pragma unroll
      for (int g = 0; g < 4; ++g) {
        #pragma unroll
        for (int h = 0; h < 4; ++h)
          acc[g][h] = mfma16(a[g], bb[h], acc[g][h]);
      }
    }
    #pragma unroll
    for (int h = 0; h < 4; ++h) {
      int cc = cb + h * 16 + r15;
      if (cc >= 400) continue;
      float bias = (cc < 200) ? hb[cc] : tb[cc - 200];
      #pragma unroll
      for (int g = 0; g < 4; ++g) {
        #pragma unroll
        for (int q = 0; q < 4; ++q) {
          int m = rb + g * 16 + g8 * 4 + q;
          float val = lrelu(acc[g][h][q] + bias);
          if (cc < 200) headp[m * 320 + (cc / 40) * 64 + (cc % 40)] = f2h(val);
          else          tail16[m * 224 + (cc - 200)] = f2h(val);
        }
      }
    }
    return;
  }
  // ---- prep items
  int t = (bid - 28) * 256 + threadIdx.x;
  if (t < 6144) { // tail16 k-pad zeros [200,224)
    int r = t / 6, j = t % 6;
    *reinterpret_cast<uint2*>(tail16 + r * 224 + 200 + j * 4) = make_uint2(0u, 0u);
    return;
  }
  t -= 6144;
  if (t < 30720) { // headp x-pad zeros [40,64) per head-group
    int r = t / 30, rem = t % 30, h = rem / 6, j = rem % 6;
    *reinterpret_cast<uint2*>(headp + r * 320 + h * 64 + 40 + j * 4) = make_uint2(0u, 0u);
    return;
  }
  t -= 30720;
  if (t < 73728) { // P16 k-pad zeros [200,224)
    int row = t / 6, j = t % 6;
    *reinterpret_cast<uint2*>(P16 + row * 224 + 200 + j * 4) = make_uint2(0u, 0u);
    return;
  }
  t -= 73728;
  if (t < 3840) { // DWhp[o][kpos] = sum_kk dw[o,kk]*W[kk, h*40+x]  (x<40, else 0)
    int kpos = t / 12, o = t % 12;
    int h = kpos >> 6, x = kpos & 63;
    float acc = 0.f;
    if (x < 40) {
      int col = h * 40 + x;
      for (int kk = 0; kk < 200; ++kk) acc += dw[o * 200 + kk] * W[kk * 427 + col];
    }
    DWhp[o * 320 + kpos] = f2h(acc);
    return;
  }
  t -= 3840;
  if (t < 2688) { // DWtp[o][k] = sum_kk dw[o,kk]*W[kk, 201+k]  (k<200, else 0)
    int k = t / 12, o = t % 12;
    float acc = 0.f;
    if (k < 200) {
      for (int kk = 0; kk < 200; ++kk) acc += dw[o * 200 + kk] * W[kk * 427 + 201 + k];
    }
    DWtp[o * 224 + k] = f2h(acc);
    return;
  }
  t -= 2688;
  if (t < 24) { // ones-column biases: W[:,200] and W[:,401]
    int o = t % 12;
    int col = (t < 12) ? 200 : 401;
    float acc = 0.f;
    for (int kk = 0; kk < 200; ++kk) acc += dw[o * 200 + kk] * W[kk * 427 + col];
    if (t < 12) biasH[o] = acc; else biasT[o] = acc;
    return;
  }
  t -= 24;
  if (t < 300) { // DWs[o][s] = sum_kk dw[o,kk]*W[kk,402+s]
    int o = t / 25, s = t % 25;
    float acc = 0.f;
    for (int kk = 0; kk < 200; ++kk) acc += dw[o * 200 + kk] * W[kk * 427 + 402 + s];
    DWs[t] = acc;
    return;
  }
  t -= 300;
  if (t < 153600) { // Gp[h][c=o*40+y][x] = sum_d dw[o,h*40+d]*U[h,d,x,y] (x<40 else 0)
    int h = t / 30720, r1 = t % 30720;
    int x = r1 / 480, r2 = r1 % 480, o = r2 / 40, y = r2 % 40;
    float acc = 0.f;
    if (x < 40) {
      #pragma unroll 8
      for (int d = 0; d < 40; ++d)
        acc += dw[o * 200 + h * 40 + d] * U[((h * 40 + d) * 40 + x) * 40 + y];
    }
    Gp[(h * 480 + o * 40 + y) * 64 + x] = f2h(acc);
    return;
  }
}

// ================= K2: P / A / Bt / E as wave-tiles, no LDS =================
__global__ void __launch_bounds__(256) k2(
    const unsigned short* __restrict__ headp, const unsigned short* __restrict__ tail16,
    const unsigned short* __restrict__ Gp, const unsigned short* __restrict__ DWhp,
    const unsigned short* __restrict__ DWtp, const float* __restrict__ biasH,
    const float* __restrict__ biasT, const float* __restrict__ se,
    const float* __restrict__ DWs, unsigned short* __restrict__ P16,
    float* __restrict__ A_ws, float* __restrict__ Bt_ws, float* __restrict__ E)
{
  int w = blockIdx.x * 4 + (threadIdx.x >> 6);
  int lane = threadIdx.x & 63, r15 = lane & 15, g8 = lane >> 4;

  if (w < 640) { // ---- P: per head-group h, [1024x64]_h x Gp_h[480x64]^T
    int h = w >> 7, rem = w & 127, mt = rem >> 3, nt = rem & 7;
    const uint4* aptr[4];
    #pragma unroll
    for (int g = 0; g < 4; ++g)
      aptr[g] = reinterpret_cast<const uint4*>(headp + (mt * 64 + g * 16 + r15) * 320 + h * 64);
    const uint4* bptr[4];
    #pragma unroll
    for (int hh = 0; hh < 4; ++hh) {
      int cc = nt * 64 + hh * 16 + r15;
      int rcl = cc < 479 ? cc : 479;
      bptr[hh] = reinterpret_cast<const uint4*>(Gp + (h * 480 + rcl) * 64);
    }
    f32x4 acc[4][4] = {};
    #pragma unroll
    for (int ks = 0; ks < 2; ++ks) {
      int idx = ks * 4 + g8;
      half8 a[4], bb[4];
      #pragma unroll
      for (int g = 0; g < 4; ++g) a[g] = __builtin_bit_cast(half8, aptr[g][idx]);
      #pragma unroll
      for (int hh = 0; hh < 4; ++hh) bb[hh] = __builtin_bit_cast(half8, bptr[hh][idx]);
      #pragma unroll
      for (int g = 0; g < 4; ++g) {
        #pragma unroll
        for (int hh = 0; hh < 4; ++hh)
          acc[g][hh] = mfma16(a[g], bb[hh], acc[g][hh]);
      }
    }
    #pragma unroll
    for (int hh = 0; hh < 4; ++hh) {
      int cc = nt * 64 + hh * 16 + r15;
      if (cc >= 480) continue;
      int o = cc / 40, y = cc % 40;
      #pragma unroll
      for (int g = 0; g < 4; ++g) {
        #pragma unroll
        for (int q = 0; q < 4; ++q) {
          int r = mt * 64 + g * 16 + g8 * 4 + q;
          P16[(r * 12 + o) * 224 + h * 40 + y] = f2h(acc[g][hh][q]);
        }
      }
    }
  } else if (w < 656) { // ---- A: [1024x320] x DWhp[12(16)x320]^T
    int mt = w - 640;
    const uint4* aptr[4];
    #pragma unroll
    for (int g = 0; g < 4; ++g)
      aptr[g] = reinterpret_cast<const uint4*>(headp + (mt * 64 + g * 16 + r15) * 320);
    int brow = r15 < 11 ? r15 : 11;
    const uint4* bptr = reinterpret_cast<const uint4*>(DWhp + brow * 320);
    f32x4 acc[4] = {};
    #pragma unroll
    for (int ks = 0; ks < 10; ++ks) {
      int idx = ks * 4 + g8;
      half8 bb = __builtin_bit_cast(half8, bptr[idx]);
      #pragma unroll
      for (int g = 0; g < 4; ++g) {
        half8 a = __builtin_bit_cast(half8, aptr[g][idx]);
        acc[g] = mfma16(a, bb, acc[g]);
      }
    }
    if (r15 < 12) {
      float bv = biasH[r15];
      #pragma unroll
      for (int g = 0; g < 4; ++g) {
        #pragma unroll
        for (int q = 0; q < 4; ++q) {
          int r = mt * 64 + g * 16 + g8 * 4 + q;
          A_ws[((r >> 8) * 12 + r15) * 256 + (r & 255)] = acc[g][q] + bv;
        }
      }
    }
  } else if (w < 672) { // ---- Bt: [1024x224] x DWtp[12(16)x224]^T
    int mt = w - 656;
    const uint4* aptr[4];
    #pragma unroll
    for (int g = 0; g < 4; ++g)
      aptr[g] = reinterpret_cast<const uint4*>(tail16 + (mt * 64 + g * 16 + r15) * 224);
    int brow = r15 < 11 ? r15 : 11;
    const uint4* bptr = reinterpret_cast<const uint4*>(DWtp + brow * 224);
    f32x4 acc[4] = {};
    #pragma unroll
    for (int ks = 0; ks < 7; ++ks) {
      int idx = ks * 4 + g8;
      half8 bb = __builtin_bit_cast(half8, bptr[idx]);
      #pragma unroll
      for (int g = 0; g < 4; ++g) {
        half8 a = __builtin_bit_cast(half8, aptr[g][idx]);
        acc[g] = mfma16(a, bb, acc[g]);
      }
    }
    if (r15 < 12) {
      float bv = biasT[r15];
      #pragma unroll
      for (int g = 0; g < 4; ++g) {
        #pragma unroll
        for (int q = 0; q < 4; ++q) {
          int r = mt * 64 + g * 16 + g8 * 4 + q;
          Bt_ws[((r >> 8) * 12 + r15) * 256 + (r & 255)] = acc[g][q] + bv;
        }
      }
    }
  } else if (w < 678) { // ---- E[o][p] = sum_s DWs[o,s]*se[p,s]
    int t2 = (w - 672) * 64 + lane;
    if (t2 < 360) {
      int o = t2 / 30, p = t2 % 30;
      float acc = 0.f;
      #pragma unroll
      for (int s = 0; s < 25; ++s) acc += DWs[o * 25 + s] * se[p * 25 + s];
      E[t2] = acc;
    }
  }
}

// ================= K3: out[b,o,m,n] = P(m,:)·tail(n,:) + A[m] + Bt[n] + E + db =================
__global__ void __launch_bounds__(256) k3(
    const unsigned short* __restrict__ P16, const unsigned short* __restrict__ tail16,
    const float* __restrict__ A_ws, const float* __restrict__ Bt_ws,
    const float* __restrict__ E, const float* __restrict__ db,
    float* __restrict__ out)
{
  int w = blockIdx.x * 4 + (threadIdx.x >> 6);
  int lane = threadIdx.x & 63, r15 = lane & 15, g8 = lane >> 4;
  int nt = w & 3, mt = (w >> 2) & 3, bo = w >> 4;
  int o = bo % 12, b = bo / 12;

  const uint4* aptr[4];
  #pragma unroll
  for (int g = 0; g < 4; ++g)
    aptr[g] = reinterpret_cast<const uint4*>(
        P16 + ((b * 256 + mt * 64 + g * 16 + r15) * 12 + o) * 224);
  const uint4* bptr[4];
  #pragma unroll
  for (int h = 0; h < 4; ++h)
    bptr[h] = reinterpret_cast<const uint4*>(
        tail16 + (b * 256 + nt * 64 + h * 16 + r15) * 224);

  f32x4 acc[4][4] = {};
  #pragma unroll
  for (int ks = 0; ks < 7; ++ks) {
    int idx = ks * 4 + g8;
    half8 a[4], bb[4];
    #pragma unroll
    for (int g = 0; g < 4; ++g) a[g] = __builtin_bit_cast(half8, aptr[g][idx]);
    #pragma unroll
    for (int h = 0; h < 4; ++h) bb[h] = __builtin_bit_cast(half8, bptr[h][idx]);
    #pragma unroll
    for (int g = 0; g < 4; ++g) {
      #pragma unroll
      for (int h = 0; h < 4; ++h)
        acc[g][h] = mfma16(a[g], bb[h], acc[g][h]);
    }
  }
  const float dbv = db[o];
  const float* Arow = A_ws + (b * 12 + o) * 256;
  const float* Btrow = Bt_ws + (b * 12 + o) * 256;
  const float* Erow = E + o * 30;
  #pragma unroll
  for (int g = 0; g < 4; ++g) {
    #pragma unroll
    for (int q = 0; q < 4; ++q) {
      int m = mt * 64 + g * 16 + g8 * 4 + q;
      float am = Arow[m] + dbv;
      #pragma unroll
      for (int h = 0; h < 4; ++h) {
        int n = nt * 64 + h * 16 + r15;
        int dpos = n - m;
        dpos = (dpos < -15) ? -15 : (dpos > 14 ? 14 : dpos);
        out[((b * 12 + o) * 256 + m) * 256 + n] = acc[g][h][q] + am + Btrow[n] + Erow[dpos + 15];
      }
    }
  }
}

extern "C" void kernel_launch(void* const* d_in, const int* in_sizes, int n_in,
                              void* d_out, int out_size, void* d_ws, size_t ws_size,
                              hipStream_t stream) {
  (void)in_sizes; (void)n_in; (void)out_size; (void)ws_size;
  const float* wr = (const float*)d_in[0];
  const float* hw = (const float*)d_in[4];
  const float* hb = (const float*)d_in[5];
  const float* tw = (const float*)d_in[6];
  const float* tb = (const float*)d_in[7];
  const float* U  = (const float*)d_in[8];
  const float* se = (const float*)d_in[9];
  const float* W  = (const float*)d_in[10];
  const float* dw = (const float*)d_in[11];
  const float* db = (const float*)d_in[12];

  char* ws = (char*)d_ws;
  unsigned short* headp  = (unsigned short*)(ws + 0);        //   655,360  [1024][320]
  unsigned short* tail16 = (unsigned short*)(ws + 655360);   //   458,752  [1024][224]
  unsigned short* P16    = (unsigned short*)(ws + 1114112);  // 5,505,024  [1024*12][224]
  float* A_ws            = (float*)(ws + 6619136);           //    49,152
  float* Bt_ws           = (float*)(ws + 6668288);           //    49,152
  unsigned short* DWhp   = (unsigned short*)(ws + 6717440);  //     7,680
  unsigned short* DWtp   = (unsigned short*)(ws + 6725120);  //     5,376
  float* biasH           = (float*)(ws + 6730496);           //        64
  float* biasT           = (float*)(ws + 6730560);           //        64
  float* E_ws            = (float*)(ws + 6730624);           //     1,440
  float* DWs             = (float*)(ws + 6732064);           //     1,200
  unsigned short* Gp     = (unsigned short*)(ws + 6733264);  //   307,200  -> end ~7.04 MB

  k1<<<1087, 256, 0, stream>>>(wr, hw, tw, hb, tb, U, W, dw,
                               headp, tail16, P16, DWhp, DWtp, biasH, biasT, DWs, Gp);
  k2<<<170, 256, 0, stream>>>(headp, tail16, Gp, DWhp, DWtp, biasH, biasT,
                              se, DWs, P16, A_ws, Bt_ws, E_ws);
  k3<<<192, 256, 0, stream>>>(P16, tail16, A_ws, Bt_ws, E_ws, db, (float*)d_out);
}

// Round 6
// 73.632 us; speedup vs baseline: 1.1387x; 1.1387x over previous
//
#include <hip/hip_runtime.h>

typedef _Float16 half8 __attribute__((ext_vector_type(8)));
typedef __fp16   fp16x2 __attribute__((ext_vector_type(2)));
typedef float    f32x4 __attribute__((ext_vector_type(4)));

#define DEV static __device__ __forceinline__

DEV unsigned short f2h(float f) {
  _Float16 h = (_Float16)f;
  return __builtin_bit_cast(unsigned short, h);
}
DEV float lrelu(float x) { return x > 0.f ? x : 0.01f * x; }
DEV f32x4 mfma16(half8 a, half8 b, f32x4 c) {
  return __builtin_amdgcn_mfma_f32_16x16x32_f16(a, b, c, 0, 0, 0);
}
DEV uint2 pk4(float4 v) {
  fp16x2 a = __builtin_amdgcn_cvt_pkrtz(v.x, v.y);
  fp16x2 b = __builtin_amdgcn_cvt_pkrtz(v.z, v.w);
  return make_uint2(__builtin_bit_cast(unsigned, a), __builtin_bit_cast(unsigned, b));
}

// dims: B=4 N=256 H=768 D=200 NH=5 HD=40 OUT=12
// padded K: head 320 (5*64), tail/P 224. Inputs f32, output f32.

// ============ kA: converts + pads + DW-precompute (coalesced) + G-precompute ============
// blocks [0,768): wr->f16 | [768,918): hw | [918,1068): tw | [1068,1500): pads
// [1500,1502): DW_all | [1502,1577): G
__global__ void __launch_bounds__(256) kA(
    const float* __restrict__ wr, const float* __restrict__ hw,
    const float* __restrict__ tw, const float* __restrict__ U,
    const float* __restrict__ W, const float* __restrict__ dw,
    unsigned short* __restrict__ wr16, unsigned short* __restrict__ hw16,
    unsigned short* __restrict__ tw16, unsigned short* __restrict__ headp,
    unsigned short* __restrict__ tail16, unsigned short* __restrict__ P16,
    unsigned short* __restrict__ DWhp, unsigned short* __restrict__ DWtp,
    float* __restrict__ biasH, float* __restrict__ biasT,
    float* __restrict__ DWs, unsigned short* __restrict__ Gp)
{
  int bid = blockIdx.x, tid = threadIdx.x;
  if (bid < 768) {            // wr -> f16, 1 float4/thread
    int t = bid * 256 + tid;
    reinterpret_cast<uint2*>(wr16)[t] = pk4(reinterpret_cast<const float4*>(wr)[t]);
    return;
  }
  if (bid < 918) {            // hw -> f16
    int t = (bid - 768) * 256 + tid;
    reinterpret_cast<uint2*>(hw16)[t] = pk4(reinterpret_cast<const float4*>(hw)[t]);
    return;
  }
  if (bid < 1068) {           // tw -> f16
    int t = (bid - 918) * 256 + tid;
    reinterpret_cast<uint2*>(tw16)[t] = pk4(reinterpret_cast<const float4*>(tw)[t]);
    return;
  }
  if (bid < 1500) {           // pad zeros
    int t = (bid - 1068) * 256 + tid;
    if (t < 6144) {           // tail16 k-pad [200,224)
      int r = t / 6, j = t % 6;
      *reinterpret_cast<uint2*>(tail16 + r * 224 + 200 + j * 4) = make_uint2(0u, 0u);
      return;
    }
    t -= 6144;
    if (t < 30720) {          // headp x-pad [40,64) per head-group
      int r = t / 30, rem = t % 30, h = rem / 6, j = rem % 6;
      *reinterpret_cast<uint2*>(headp + r * 320 + h * 64 + 40 + j * 4) = make_uint2(0u, 0u);
      return;
    }
    t -= 30720;
    if (t < 73728) {          // P16 k-pad [200,224)
      int row = t / 6, j = t % 6;
      *reinterpret_cast<uint2*>(P16 + row * 224 + 200 + j * 4) = make_uint2(0u, 0u);
      return;
    }
    return;
  }
  if (bid < 1502) {           // DW_all[o,col] = sum_kk dw[o,kk]*W[kk,col], col coalesced
    __shared__ float dws[2400];
    const float4* dwf4 = reinterpret_cast<const float4*>(dw);
    float4* lds4 = reinterpret_cast<float4*>(dws);
    for (int j = tid; j < 600; j += 256) lds4[j] = dwf4[j];
    __syncthreads();
    int col = (bid - 1500) * 256 + tid;
    if (col >= 427) return;
    float acc[12] = {};
    for (int kk = 0; kk < 200; ++kk) {
      float wv = W[kk * 427 + col];
      #pragma unroll
      for (int o = 0; o < 12; ++o) acc[o] += dws[o * 200 + kk] * wv;
    }
    if (col < 200) {
      int h = col / 40, x = col % 40;
      #pragma unroll
      for (int o = 0; o < 12; ++o) DWhp[o * 320 + h * 64 + x] = f2h(acc[o]);
    } else if (col == 200) {
      #pragma unroll
      for (int o = 0; o < 12; ++o) biasH[o] = acc[o];
    } else if (col < 401) {
      int k = col - 201;
      #pragma unroll
      for (int o = 0; o < 12; ++o) DWtp[o * 224 + k] = f2h(acc[o]);
    } else if (col == 401) {
      #pragma unroll
      for (int o = 0; o < 12; ++o) biasT[o] = acc[o];
    } else {
      int s = col - 402;
      #pragma unroll
      for (int o = 0; o < 12; ++o) DWs[o * 25 + s] = acc[o];
    }
    return;
  }
  { // G: Gp[h][c=o*40+y][x] = sum_d dw[o,h*40+d]*U[h,d,x,y]; 8 x per thread, coalesced write
    int t = (bid - 1502) * 256 + tid;          // 19200 threads
    int h = t / 3840, r = t % 3840;
    int c = r >> 3, xo = r & 7;
    int o = c / 40, y = c % 40;
    unsigned short outv[8];
    if (xo < 5) {
      float acc8[8] = {};
      for (int d = 0; d < 40; ++d) {
        float dv = dw[o * 200 + h * 40 + d];
        int base = ((h * 40 + d) * 40 + xo * 8) * 40 + y;
        #pragma unroll
        for (int xi = 0; xi < 8; ++xi) acc8[xi] += dv * U[base + xi * 40];
      }
      #pragma unroll
      for (int xi = 0; xi < 8; ++xi) outv[xi] = f2h(acc8[xi]);
    } else {
      #pragma unroll
      for (int xi = 0; xi < 8; ++xi) outv[xi] = 0;
    }
    *reinterpret_cast<uint4*>(Gp + (h * 480 + c) * 64 + xo * 8) =
        *reinterpret_cast<const uint4*>(outv);
    return;
  }
}

// ---------------- GEMM1: [1024x768] x [400x768]^T -> leaky_relu -> headp/tail16 ----------------
__global__ void __launch_bounds__(64) k_gemm1(
    const unsigned short* __restrict__ wr16, const unsigned short* __restrict__ hw16,
    const unsigned short* __restrict__ tw16, const float* __restrict__ hb,
    const float* __restrict__ tb, unsigned short* __restrict__ headp,
    unsigned short* __restrict__ tail16)
{
  __shared__ __align__(16) unsigned short Xs[64 * 136];
  __shared__ __align__(16) unsigned short Wsh[64 * 136];
  int bid = blockIdx.x;
  int mt = bid / 7, nt = bid % 7;
  int lane = threadIdx.x, r15 = lane & 15, g8 = lane >> 4;
  int rb = mt * 64, cb = nt * 64;
  int c = cb + lane;

  f32x4 acc[4][4] = {};

  for (int kt = 0; kt < 6; ++kt) {
    int k0 = kt * 128;
    {
      const uint4* s = reinterpret_cast<const uint4*>(wr16 + (rb + lane) * 768 + k0);
      uint4* d = reinterpret_cast<uint4*>(&Xs[lane * 136]);
      #pragma unroll
      for (int j = 0; j < 16; ++j) d[j] = s[j];
    }
    {
      uint4* d = reinterpret_cast<uint4*>(&Wsh[lane * 136]);
      if (c < 200) {
        const uint4* s = reinterpret_cast<const uint4*>(hw16 + c * 768 + k0);
        #pragma unroll
        for (int j = 0; j < 16; ++j) d[j] = s[j];
      } else if (c < 400) {
        const uint4* s = reinterpret_cast<const uint4*>(tw16 + (c - 200) * 768 + k0);
        #pragma unroll
        for (int j = 0; j < 16; ++j) d[j] = s[j];
      } else {
        uint4 z = make_uint4(0u, 0u, 0u, 0u);
        #pragma unroll
        for (int j = 0; j < 16; ++j) d[j] = z;
      }
    }
    __syncthreads();
    #pragma unroll
    for (int ks = 0; ks < 4; ++ks) {
      half8 a[4], bb[4];
      #pragma unroll
      for (int g = 0; g < 4; ++g)
        a[g] = *reinterpret_cast<const half8*>(&Xs[(g * 16 + r15) * 136 + ks * 32 + g8 * 8]);
      #pragma unroll
      for (int h = 0; h < 4; ++h)
        bb[h] = *reinterpret_cast<const half8*>(&Wsh[(h * 16 + r15) * 136 + ks * 32 + g8 * 8]);
      #pragma unroll
      for (int g = 0; g < 4; ++g) {
        #pragma unroll
        for (int h = 0; h < 4; ++h)
          acc[g][h] = mfma16(a[g], bb[h], acc[g][h]);
      }
    }
    __syncthreads();
  }
  #pragma unroll
  for (int h = 0; h < 4; ++h) {
    int cc = cb + h * 16 + r15;
    if (cc >= 400) continue;
    float bias = (cc < 200) ? hb[cc] : tb[cc - 200];
    #pragma unroll
    for (int g = 0; g < 4; ++g) {
      #pragma unroll
      for (int q = 0; q < 4; ++q) {
        int m = rb + g * 16 + g8 * 4 + q;
        float val = lrelu(acc[g][h][q] + bias);
        if (cc < 200) headp[m * 320 + (cc / 40) * 64 + (cc % 40)] = f2h(val);
        else          tail16[m * 224 + (cc - 200)] = f2h(val);
      }
    }
  }
}

// ---------------- GEMM2: P (per head-group), A, Bt, E ----------------
__global__ void __launch_bounds__(64) k_gemm2(
    const unsigned short* __restrict__ headp, const unsigned short* __restrict__ tail16,
    const unsigned short* __restrict__ Gp, const unsigned short* __restrict__ DWhp,
    const unsigned short* __restrict__ DWtp, const float* __restrict__ biasH,
    const float* __restrict__ biasT, const float* __restrict__ se,
    const float* __restrict__ DWs, unsigned short* __restrict__ P16,
    float* __restrict__ A_ws, float* __restrict__ Bt_ws, float* __restrict__ E)
{
  __shared__ __align__(16) unsigned short sm[26240];
  int bid = blockIdx.x;
  int lane = threadIdx.x, r15 = lane & 15, g8 = lane >> 4;

  if (bid < 640) { // P: [1024 x 64]_h x [480 x 64]^T per head-group h
    int h = bid / 128, rem = bid % 128, mt = rem >> 3, nt = rem & 7;
    unsigned short* As = sm;
    unsigned short* Bs = sm + 64 * 72;
    {
      const uint4* s = reinterpret_cast<const uint4*>(headp + (mt * 64 + lane) * 320 + h * 64);
      uint4* d = reinterpret_cast<uint4*>(&As[lane * 72]);
      #pragma unroll
      for (int j = 0; j < 8; ++j) d[j] = s[j];
    }
    {
      int cc = nt * 64 + lane;
      uint4* d = reinterpret_cast<uint4*>(&Bs[lane * 72]);
      if (cc < 480) {
        const uint4* s = reinterpret_cast<const uint4*>(Gp + (h * 480 + cc) * 64);
        #pragma unroll
        for (int j = 0; j < 8; ++j) d[j] = s[j];
      } else {
        uint4 z = make_uint4(0u, 0u, 0u, 0u);
        #pragma unroll
        for (int j = 0; j < 8; ++j) d[j] = z;
      }
    }
    __syncthreads();
    f32x4 acc[4][4] = {};
    #pragma unroll
    for (int ks = 0; ks < 2; ++ks) {
      half8 a[4], bb[4];
      #pragma unroll
      for (int g = 0; g < 4; ++g)
        a[g] = *reinterpret_cast<const half8*>(&As[(g * 16 + r15) * 72 + ks * 32 + g8 * 8]);
      #pragma unroll
      for (int hh = 0; hh < 4; ++hh)
        bb[hh] = *reinterpret_cast<const half8*>(&Bs[(hh * 16 + r15) * 72 + ks * 32 + g8 * 8]);
      #pragma unroll
      for (int g = 0; g < 4; ++g) {
        #pragma unroll
        for (int hh = 0; hh < 4; ++hh)
          acc[g][hh] = mfma16(a[g], bb[hh], acc[g][hh]);
      }
    }
    #pragma unroll
    for (int hh = 0; hh < 4; ++hh) {
      int cc = nt * 64 + hh * 16 + r15;
      if (cc >= 480) continue;
      int o = cc / 40, y = cc % 40;
      #pragma unroll
      for (int g = 0; g < 4; ++g) {
        #pragma unroll
        for (int q = 0; q < 4; ++q) {
          int r = mt * 64 + g * 16 + g8 * 4 + q;
          P16[(r * 12 + o) * 224 + h * 40 + y] = f2h(acc[g][hh][q]);
        }
      }
    }
  } else if (bid < 656) { // A: [1024 x 320] x [12(16) x 320]^T
    int mt = bid - 640;
    unsigned short* As = sm;
    unsigned short* Bs = sm + 64 * 328;
    {
      const uint4* s = reinterpret_cast<const uint4*>(headp + (mt * 64 + lane) * 320);
      uint4* d = reinterpret_cast<uint4*>(&As[lane * 328]);
      #pragma unroll
      for (int j = 0; j < 40; ++j) d[j] = s[j];
    }
    #pragma unroll
    for (int tt = 0; tt < 10; ++tt) {
      int idx = tt * 64 + lane;
      int row = idx / 40, j = idx % 40;
      uint4 v = make_uint4(0u, 0u, 0u, 0u);
      if (row < 12) v = reinterpret_cast<const uint4*>(DWhp + row * 320)[j];
      reinterpret_cast<uint4*>(&Bs[row * 328])[j] = v;
    }
    __syncthreads();
    f32x4 acc[4] = {};
    #pragma unroll
    for (int ks = 0; ks < 10; ++ks) {
      half8 bb = *reinterpret_cast<const half8*>(&Bs[r15 * 328 + ks * 32 + g8 * 8]);
      #pragma unroll
      for (int g = 0; g < 4; ++g) {
        half8 a = *reinterpret_cast<const half8*>(&As[(g * 16 + r15) * 328 + ks * 32 + g8 * 8]);
        acc[g] = mfma16(a, bb, acc[g]);
      }
    }
    if (r15 < 12) {
      float bv = biasH[r15];
      #pragma unroll
      for (int g = 0; g < 4; ++g) {
        #pragma unroll
        for (int q = 0; q < 4; ++q) {
          int r = mt * 64 + g * 16 + g8 * 4 + q;
          A_ws[((r >> 8) * 12 + r15) * 256 + (r & 255)] = acc[g][q] + bv;
        }
      }
    }
  } else if (bid < 672) { // Bt: [1024 x 224] x [12(16) x 224]^T
    int mt = bid - 656;
    unsigned short* As = sm;
    unsigned short* Bs = sm + 64 * 232;
    {
      const uint4* s = reinterpret_cast<const uint4*>(tail16 + (mt * 64 + lane) * 224);
      uint4* d = reinterpret_cast<uint4*>(&As[lane * 232]);
      #pragma unroll
      for (int j = 0; j < 28; ++j) d[j] = s[j];
    }
    #pragma unroll
    for (int tt = 0; tt < 7; ++tt) {
      int idx = tt * 64 + lane;
      int row = idx / 28, j = idx % 28;
      uint4 v = make_uint4(0u, 0u, 0u, 0u);
      if (row < 12) v = reinterpret_cast<const uint4*>(DWtp + row * 224)[j];
      reinterpret_cast<uint4*>(&Bs[row * 232])[j] = v;
    }
    __syncthreads();
    f32x4 acc[4] = {};
    #pragma unroll
    for (int ks = 0; ks < 7; ++ks) {
      half8 bb = *reinterpret_cast<const half8*>(&Bs[r15 * 232 + ks * 32 + g8 * 8]);
      #pragma unroll
      for (int g = 0; g < 4; ++g) {
        half8 a = *reinterpret_cast<const half8*>(&As[(g * 16 + r15) * 232 + ks * 32 + g8 * 8]);
        acc[g] = mfma16(a, bb, acc[g]);
      }
    }
    if (r15 < 12) {
      float bv = biasT[r15];
      #pragma unroll
      for (int g = 0; g < 4; ++g) {
        #pragma unroll
        for (int q = 0; q < 4; ++q) {
          int r = mt * 64 + g * 16 + g8 * 4 + q;
          Bt_ws[((r >> 8) * 12 + r15) * 256 + (r & 255)] = acc[g][q] + bv;
        }
      }
    }
  } else { // E[o][p] = sum_s DWs[o,s]*se[p,s]
    int t2 = (bid - 672) * 64 + lane;
    if (t2 < 360) {
      int o = t2 / 30, p = t2 % 30;
      float acc = 0.f;
      #pragma unroll
      for (int s = 0; s < 25; ++s) acc += DWs[o * 25 + s] * se[p * 25 + s];
      E[t2] = acc;
    }
  }
}

// ---------------- main: out[b,o,m,n] = P(m,:)·tail(n,:) + A[m] + Bt[n] + E[span] + db ----------------
__global__ void __launch_bounds__(64) k_main(
    const unsigned short* __restrict__ P16, const unsigned short* __restrict__ tail16,
    const float* __restrict__ A_ws, const float* __restrict__ Bt_ws,
    const float* __restrict__ E, const float* __restrict__ db,
    float* __restrict__ out)
{
  __shared__ __align__(16) unsigned short Ps[64 * 232];
  __shared__ __align__(16) unsigned short Ts[64 * 232];
  int bid = blockIdx.x;
  int nt = bid & 3, mt = (bid >> 2) & 3, bo = bid >> 4;
  int o = bo % 12, b = bo / 12;
  int lane = threadIdx.x, r15 = lane & 15, g8 = lane >> 4;
  {
    const uint4* s = reinterpret_cast<const uint4*>(P16 + ((b * 256 + mt * 64 + lane) * 12 + o) * 224);
    uint4* d = reinterpret_cast<uint4*>(&Ps[lane * 232]);
    #pragma unroll
    for (int j = 0; j < 28; ++j) d[j] = s[j];
    const uint4* s2 = reinterpret_cast<const uint4*>(tail16 + (b * 256 + nt * 64 + lane) * 224);
    uint4* d2 = reinterpret_cast<uint4*>(&Ts[lane * 232]);
    #pragma unroll
    for (int j = 0; j < 28; ++j) d2[j] = s2[j];
  }
  __syncthreads();
  f32x4 acc[4][4] = {};
  #pragma unroll
  for (int ks = 0; ks < 7; ++ks) {
    half8 a[4], bb[4];
    #pragma unroll
    for (int g = 0; g < 4; ++g)
      a[g] = *reinterpret_cast<const half8*>(&Ps[(g * 16 + r15) * 232 + ks * 32 + g8 * 8]);
    #pragma unroll
    for (int h = 0; h < 4; ++h)
      bb[h] = *reinterpret_cast<const half8*>(&Ts[(h * 16 + r15) * 232 + ks * 32 + g8 * 8]);
    #pragma unroll
    for (int g = 0; g < 4; ++g) {
      #pragma unroll
      for (int h = 0; h < 4; ++h)
        acc[g][h] = mfma16(a[g], bb[h], acc[g][h]);
    }
  }
  const float dbv = db[o];
  const float* Arow = A_ws + (b * 12 + o) * 256;
  const float* Btrow = Bt_ws + (b * 12 + o) * 256;
  const float* Erow = E + o * 30;
  #pragma unroll
  for (int g = 0; g < 4; ++g) {
    #pragma unroll
    for (int q = 0; q < 4; ++q) {
      int m = mt * 64 + g * 16 + g8 * 4 + q;
      float am = Arow[m] + dbv;
      #pragma unroll
      for (int h = 0; h < 4; ++h) {
        int n = nt * 64 + h * 16 + r15;
        int dpos = n - m;
        dpos = (dpos < -15) ? -15 : (dpos > 14 ? 14 : dpos);
        out[((b * 12 + o) * 256 + m) * 256 + n] = acc[g][h][q] + am + Btrow[n] + Erow[dpos + 15];
      }
    }
  }
}

extern "C" void kernel_launch(void* const* d_in, const int* in_sizes, int n_in,
                              void* d_out, int out_size, void* d_ws, size_t ws_size,
                              hipStream_t stream) {
  (void)in_sizes; (void)n_in; (void)out_size; (void)ws_size;
  const float* wr = (const float*)d_in[0];
  const float* hw = (const float*)d_in[4];
  const float* hb = (const float*)d_in[5];
  const float* tw = (const float*)d_in[6];
  const float* tb = (const float*)d_in[7];
  const float* U  = (const float*)d_in[8];
  const float* se = (const float*)d_in[9];
  const float* W  = (const float*)d_in[10];
  const float* dw = (const float*)d_in[11];
  const float* db = (const float*)d_in[12];

  char* ws = (char*)d_ws;
  unsigned short* wr16   = (unsigned short*)(ws + 0);        // 1,572,864 B
  unsigned short* hw16   = (unsigned short*)(ws + 1572864);  //   307,200
  unsigned short* tw16   = (unsigned short*)(ws + 1880064);  //   307,200
  unsigned short* headp  = (unsigned short*)(ws + 2187264);  //   655,360  [1024][320]
  unsigned short* tail16 = (unsigned short*)(ws + 2842624);  //   458,752  [1024][224]
  unsigned short* P16    = (unsigned short*)(ws + 3301376);  // 5,505,024  [1024*12][224]
  float* A_ws            = (float*)(ws + 8806400);           //    49,152
  float* Bt_ws           = (float*)(ws + 8855552);           //    49,152
  unsigned short* DWhp   = (unsigned short*)(ws + 8904704);  //     7,680
  unsigned short* DWtp   = (unsigned short*)(ws + 8912384);  //     5,376
  float* biasH           = (float*)(ws + 8917760);           //        64
  float* biasT           = (float*)(ws + 8917824);           //        64
  float* E_ws            = (float*)(ws + 8917888);           //     1,440
  float* DWs             = (float*)(ws + 8919328);           //     1,200
  unsigned short* Gp     = (unsigned short*)(ws + 8920528);  //   307,200  -> end ~9.23 MB

  kA<<<1577, 256, 0, stream>>>(wr, hw, tw, U, W, dw,
                               wr16, hw16, tw16, headp, tail16, P16,
                               DWhp, DWtp, biasH, biasT, DWs, Gp);
  k_gemm1<<<112, 64, 0, stream>>>(wr16, hw16, tw16, hb, tb, headp, tail16);
  k_gemm2<<<678, 64, 0, stream>>>(headp, tail16, Gp, DWhp, DWtp, biasH, biasT,
                                  se, DWs, P16, A_ws, Bt_ws, E_ws);
  k_main<<<768, 64, 0, stream>>>(P16, tail16, A_ws, Bt_ws, E_ws, db,
                                 (float*)d_out);
}

// Round 7
// 58.496 us; speedup vs baseline: 1.4334x; 1.2588x over previous
//
#include <hip/hip_runtime.h>

typedef _Float16 half8 __attribute__((ext_vector_type(8)));
typedef __fp16   fp16x2 __attribute__((ext_vector_type(2)));
typedef float    f32x4 __attribute__((ext_vector_type(4)));

#define DEV static __device__ __forceinline__

DEV unsigned short f2h(float f) {
  _Float16 h = (_Float16)f;
  return __builtin_bit_cast(unsigned short, h);
}
DEV float lrelu(float x) { return x > 0.f ? x : 0.01f * x; }
DEV f32x4 mfma16(half8 a, half8 b, f32x4 c) {
  return __builtin_amdgcn_mfma_f32_16x16x32_f16(a, b, c, 0, 0, 0);
}
DEV uint2 pk4(float4 v) {
  fp16x2 a = __builtin_amdgcn_cvt_pkrtz(v.x, v.y);
  fp16x2 b = __builtin_amdgcn_cvt_pkrtz(v.z, v.w);
  return make_uint2(__builtin_bit_cast(unsigned, a), __builtin_bit_cast(unsigned, b));
}

// dims: B=4 N=256 H=768 D=200 NH=5 HD=40 OUT=12
// padded K: head 320 (5*64), tail/P 224. Inputs f32, output f32.

// ============ kA: conversions + pads + DW (wave-parallel) + G (short-chain) ============
// blocks [0,768): wr | [768,918): hw | [918,1068): tw | [1068,1558): pads
// [1558,1665): DW wave-per-col | [1665,1697): G thread-per-(h,x,y)
__global__ void __launch_bounds__(256) kA(
    const float* __restrict__ wr, const float* __restrict__ hw,
    const float* __restrict__ tw, const float* __restrict__ U,
    const float* __restrict__ W, const float* __restrict__ dw,
    unsigned short* __restrict__ wr16, unsigned short* __restrict__ hw16,
    unsigned short* __restrict__ tw16, unsigned short* __restrict__ headp,
    unsigned short* __restrict__ tail16, unsigned short* __restrict__ P16,
    unsigned short* __restrict__ DWhp, unsigned short* __restrict__ DWtp,
    float* __restrict__ biasH, float* __restrict__ biasT,
    float* __restrict__ DWs, unsigned short* __restrict__ Gp)
{
  int bid = blockIdx.x, tid = threadIdx.x;
  if (bid < 768) {            // wr -> f16, 1 float4/thread
    int t = bid * 256 + tid;
    reinterpret_cast<uint2*>(wr16)[t] = pk4(reinterpret_cast<const float4*>(wr)[t]);
    return;
  }
  if (bid < 918) {            // hw -> f16
    int t = (bid - 768) * 256 + tid;
    reinterpret_cast<uint2*>(hw16)[t] = pk4(reinterpret_cast<const float4*>(hw)[t]);
    return;
  }
  if (bid < 1068) {           // tw -> f16
    int t = (bid - 918) * 256 + tid;
    reinterpret_cast<uint2*>(tw16)[t] = pk4(reinterpret_cast<const float4*>(tw)[t]);
    return;
  }
  if (bid < 1558) {           // pad zeros (all uint2 = 8B stores)
    int t = (bid - 1068) * 256 + tid;
    if (t < 6144) {           // tail16 k-pad [200,224)
      int r = t / 6, j = t % 6;
      *reinterpret_cast<uint2*>(tail16 + r * 224 + 200 + j * 4) = make_uint2(0u, 0u);
      return;
    }
    t -= 6144;
    if (t < 30720) {          // headp x-pad [40,64) per head-group
      int r = t / 30, rem = t % 30, h = rem / 6, j = rem % 6;
      *reinterpret_cast<uint2*>(headp + r * 320 + h * 64 + 40 + j * 4) = make_uint2(0u, 0u);
      return;
    }
    t -= 30720;
    if (t < 73728) {          // P16 k-pad [200,224)
      int row = t / 6, j = t % 6;
      *reinterpret_cast<uint2*>(P16 + row * 224 + 200 + j * 4) = make_uint2(0u, 0u);
      return;
    }
    t -= 73728;
    if (t < 14400) {          // Gp x-pad [40,64) for all 2400 rows
      int row = t / 6, j = t % 6;
      *reinterpret_cast<uint2*>(Gp + row * 64 + 40 + j * 4) = make_uint2(0u, 0u);
      return;
    }
    t -= 14400;
    if (t < 360) {            // DWhp x-pad [40,64) per (o,h)
      int ro = t / 6, j = t % 6, o = ro / 5, h = ro % 5;
      *reinterpret_cast<uint2*>(DWhp + o * 320 + h * 64 + 40 + j * 4) = make_uint2(0u, 0u);
      return;
    }
    t -= 360;
    if (t < 72) {             // DWtp k-pad [200,224)
      int o = t / 6, j = t % 6;
      *reinterpret_cast<uint2*>(DWtp + o * 224 + 200 + j * 4) = make_uint2(0u, 0u);
      return;
    }
    return;
  }
  if (bid < 1665) {           // DW: wave-per-column, lane-split K (chain = 4 indep loads)
    __shared__ float dws[2400];
    const float4* dwf4 = reinterpret_cast<const float4*>(dw);
    float4* lds4 = reinterpret_cast<float4*>(dws);
    for (int j = tid; j < 600; j += 256) lds4[j] = dwf4[j];
    __syncthreads();
    int col = (bid - 1558) * 4 + (tid >> 6);
    if (col >= 427) return;
    int lane = tid & 63;
    float wv0 = W[lane * 427 + col];
    float wv1 = W[(lane + 64) * 427 + col];
    float wv2 = W[(lane + 128) * 427 + col];
    float wv3 = (lane < 8) ? W[(lane + 192) * 427 + col] : 0.f;
    float acc[12];
    #pragma unroll
    for (int o = 0; o < 12; ++o) {
      const float* dr = &dws[o * 200];
      float a = dr[lane] * wv0 + dr[lane + 64] * wv1 + dr[lane + 128] * wv2;
      if (lane < 8) a += dr[lane + 192] * wv3;
      acc[o] = a;
    }
    #pragma unroll
    for (int s = 1; s < 64; s <<= 1) {
      #pragma unroll
      for (int o = 0; o < 12; ++o) acc[o] += __shfl_xor(acc[o], s, 64);
    }
    if (lane == 0) {
      if (col < 200) {
        int h = col / 40, x = col % 40;
        #pragma unroll
        for (int o = 0; o < 12; ++o) DWhp[o * 320 + h * 64 + x] = f2h(acc[o]);
      } else if (col == 200) {
        #pragma unroll
        for (int o = 0; o < 12; ++o) biasH[o] = acc[o];
      } else if (col < 401) {
        int k = col - 201;
        #pragma unroll
        for (int o = 0; o < 12; ++o) DWtp[o * 224 + k] = f2h(acc[o]);
      } else if (col == 401) {
        #pragma unroll
        for (int o = 0; o < 12; ++o) biasT[o] = acc[o];
      } else {
        int s = col - 402;
        #pragma unroll
        for (int o = 0; o < 12; ++o) DWs[o * 25 + s] = acc[o];
      }
    }
    return;
  }
  { // G: thread-per-(h,x,y); 40 independent coalesced U loads, each reused 12x
    __shared__ float dws[2400];
    const float4* dwf4 = reinterpret_cast<const float4*>(dw);
    float4* lds4 = reinterpret_cast<float4*>(dws);
    for (int j = tid; j < 600; j += 256) lds4[j] = dwf4[j];
    __syncthreads();
    int t = (bid - 1665) * 256 + tid;
    if (t >= 8000) return;
    int h = t / 1600, r = t % 1600, x = r / 40, y = r % 40;
    const float* Ub = U + ((h * 40) * 40 + x) * 40 + y;   // +1600 per d
    float acc[12] = {};
    #pragma unroll 4
    for (int d = 0; d < 40; ++d) {
      float uv = Ub[d * 1600];
      #pragma unroll
      for (int o = 0; o < 12; ++o) acc[o] += dws[o * 200 + h * 40 + d] * uv;
    }
    #pragma unroll
    for (int o = 0; o < 12; ++o)
      Gp[(h * 480 + o * 40 + y) * 64 + x] = f2h(acc[o]);
    return;
  }
}

// ---------------- GEMM1: [1024x768] x [400x768]^T -> leaky_relu -> headp/tail16 ----------------
__global__ void __launch_bounds__(64) k_gemm1(
    const unsigned short* __restrict__ wr16, const unsigned short* __restrict__ hw16,
    const unsigned short* __restrict__ tw16, const float* __restrict__ hb,
    const float* __restrict__ tb, unsigned short* __restrict__ headp,
    unsigned short* __restrict__ tail16)
{
  __shared__ __align__(16) unsigned short Xs[64 * 136];
  __shared__ __align__(16) unsigned short Wsh[64 * 136];
  int bid = blockIdx.x;
  int mt = bid / 7, nt = bid % 7;
  int lane = threadIdx.x, r15 = lane & 15, g8 = lane >> 4;
  int rb = mt * 64, cb = nt * 64;
  int c = cb + lane;

  f32x4 acc[4][4] = {};

  for (int kt = 0; kt < 6; ++kt) {
    int k0 = kt * 128;
    {
      const uint4* s = reinterpret_cast<const uint4*>(wr16 + (rb + lane) * 768 + k0);
      uint4* d = reinterpret_cast<uint4*>(&Xs[lane * 136]);
      #pragma unroll
      for (int j = 0; j < 16; ++j) d[j] = s[j];
    }
    {
      uint4* d = reinterpret_cast<uint4*>(&Wsh[lane * 136]);
      if (c < 200) {
        const uint4* s = reinterpret_cast<const uint4*>(hw16 + c * 768 + k0);
        #pragma unroll
        for (int j = 0; j < 16; ++j) d[j] = s[j];
      } else if (c < 400) {
        const uint4* s = reinterpret_cast<const uint4*>(tw16 + (c - 200) * 768 + k0);
        #pragma unroll
        for (int j = 0; j < 16; ++j) d[j] = s[j];
      } else {
        uint4 z = make_uint4(0u, 0u, 0u, 0u);
        #pragma unroll
        for (int j = 0; j < 16; ++j) d[j] = z;
      }
    }
    __syncthreads();
    #pragma unroll
    for (int ks = 0; ks < 4; ++ks) {
      half8 a[4], bb[4];
      #pragma unroll
      for (int g = 0; g < 4; ++g)
        a[g] = *reinterpret_cast<const half8*>(&Xs[(g * 16 + r15) * 136 + ks * 32 + g8 * 8]);
      #pragma unroll
      for (int h = 0; h < 4; ++h)
        bb[h] = *reinterpret_cast<const half8*>(&Wsh[(h * 16 + r15) * 136 + ks * 32 + g8 * 8]);
      #pragma unroll
      for (int g = 0; g < 4; ++g) {
        #pragma unroll
        for (int h = 0; h < 4; ++h)
          acc[g][h] = mfma16(a[g], bb[h], acc[g][h]);
      }
    }
    __syncthreads();
  }
  #pragma unroll
  for (int h = 0; h < 4; ++h) {
    int cc = cb + h * 16 + r15;
    if (cc >= 400) continue;
    float bias = (cc < 200) ? hb[cc] : tb[cc - 200];
    #pragma unroll
    for (int g = 0; g < 4; ++g) {
      #pragma unroll
      for (int q = 0; q < 4; ++q) {
        int m = rb + g * 16 + g8 * 4 + q;
        float val = lrelu(acc[g][h][q] + bias);
        if (cc < 200) headp[m * 320 + (cc / 40) * 64 + (cc % 40)] = f2h(val);
        else          tail16[m * 224 + (cc - 200)] = f2h(val);
      }
    }
  }
}

// ---------------- GEMM2: P (per head-group), A, Bt, E ----------------
__global__ void __launch_bounds__(64) k_gemm2(
    const unsigned short* __restrict__ headp, const unsigned short* __restrict__ tail16,
    const unsigned short* __restrict__ Gp, const unsigned short* __restrict__ DWhp,
    const unsigned short* __restrict__ DWtp, const float* __restrict__ biasH,
    const float* __restrict__ biasT, const float* __restrict__ se,
    const float* __restrict__ DWs, unsigned short* __restrict__ P16,
    float* __restrict__ A_ws, float* __restrict__ Bt_ws, float* __restrict__ E)
{
  __shared__ __align__(16) unsigned short sm[26240];
  int bid = blockIdx.x;
  int lane = threadIdx.x, r15 = lane & 15, g8 = lane >> 4;

  if (bid < 640) { // P: [1024 x 64]_h x [480 x 64]^T per head-group h
    int h = bid / 128, rem = bid % 128, mt = rem >> 3, nt = rem & 7;
    unsigned short* As = sm;
    unsigned short* Bs = sm + 64 * 72;
    {
      const uint4* s = reinterpret_cast<const uint4*>(headp + (mt * 64 + lane) * 320 + h * 64);
      uint4* d = reinterpret_cast<uint4*>(&As[lane * 72]);
      #pragma unroll
      for (int j = 0; j < 8; ++j) d[j] = s[j];
    }
    {
      int cc = nt * 64 + lane;
      uint4* d = reinterpret_cast<uint4*>(&Bs[lane * 72]);
      if (cc < 480) {
        const uint4* s = reinterpret_cast<const uint4*>(Gp + (h * 480 + cc) * 64);
        #pragma unroll
        for (int j = 0; j < 8; ++j) d[j] = s[j];
      } else {
        uint4 z = make_uint4(0u, 0u, 0u, 0u);
        #pragma unroll
        for (int j = 0; j < 8; ++j) d[j] = z;
      }
    }
    __syncthreads();
    f32x4 acc[4][4] = {};
    #pragma unroll
    for (int ks = 0; ks < 2; ++ks) {
      half8 a[4], bb[4];
      #pragma unroll
      for (int g = 0; g < 4; ++g)
        a[g] = *reinterpret_cast<const half8*>(&As[(g * 16 + r15) * 72 + ks * 32 + g8 * 8]);
      #pragma unroll
      for (int hh = 0; hh < 4; ++hh)
        bb[hh] = *reinterpret_cast<const half8*>(&Bs[(hh * 16 + r15) * 72 + ks * 32 + g8 * 8]);
      #pragma unroll
      for (int g = 0; g < 4; ++g) {
        #pragma unroll
        for (int hh = 0; hh < 4; ++hh)
          acc[g][hh] = mfma16(a[g], bb[hh], acc[g][hh]);
      }
    }
    #pragma unroll
    for (int hh = 0; hh < 4; ++hh) {
      int cc = nt * 64 + hh * 16 + r15;
      if (cc >= 480) continue;
      int o = cc / 40, y = cc % 40;
      #pragma unroll
      for (int g = 0; g < 4; ++g) {
        #pragma unroll
        for (int q = 0; q < 4; ++q) {
          int r = mt * 64 + g * 16 + g8 * 4 + q;
          P16[(r * 12 + o) * 224 + h * 40 + y] = f2h(acc[g][hh][q]);
        }
      }
    }
  } else if (bid < 656) { // A: [1024 x 320] x [12(16) x 320]^T
    int mt = bid - 640;
    unsigned short* As = sm;
    unsigned short* Bs = sm + 64 * 328;
    {
      const uint4* s = reinterpret_cast<const uint4*>(headp + (mt * 64 + lane) * 320);
      uint4* d = reinterpret_cast<uint4*>(&As[lane * 328]);
      #pragma unroll
      for (int j = 0; j < 40; ++j) d[j] = s[j];
    }
    #pragma unroll
    for (int tt = 0; tt < 10; ++tt) {
      int idx = tt * 64 + lane;
      int row = idx / 40, j = idx % 40;
      uint4 v = make_uint4(0u, 0u, 0u, 0u);
      if (row < 12) v = reinterpret_cast<const uint4*>(DWhp + row * 320)[j];
      reinterpret_cast<uint4*>(&Bs[row * 328])[j] = v;
    }
    __syncthreads();
    f32x4 acc[4] = {};
    #pragma unroll
    for (int ks = 0; ks < 10; ++ks) {
      half8 bb = *reinterpret_cast<const half8*>(&Bs[r15 * 328 + ks * 32 + g8 * 8]);
      #pragma unroll
      for (int g = 0; g < 4; ++g) {
        half8 a = *reinterpret_cast<const half8*>(&As[(g * 16 + r15) * 328 + ks * 32 + g8 * 8]);
        acc[g] = mfma16(a, bb, acc[g]);
      }
    }
    if (r15 < 12) {
      float bv = biasH[r15];
      #pragma unroll
      for (int g = 0; g < 4; ++g) {
        #pragma unroll
        for (int q = 0; q < 4; ++q) {
          int r = mt * 64 + g * 16 + g8 * 4 + q;
          A_ws[((r >> 8) * 12 + r15) * 256 + (r & 255)] = acc[g][q] + bv;
        }
      }
    }
  } else if (bid < 672) { // Bt: [1024 x 224] x [12(16) x 224]^T
    int mt = bid - 656;
    unsigned short* As = sm;
    unsigned short* Bs = sm + 64 * 232;
    {
      const uint4* s = reinterpret_cast<const uint4*>(tail16 + (mt * 64 + lane) * 224);
      uint4* d = reinterpret_cast<uint4*>(&As[lane * 232]);
      #pragma unroll
      for (int j = 0; j < 28; ++j) d[j] = s[j];
    }
    #pragma unroll
    for (int tt = 0; tt < 7; ++tt) {
      int idx = tt * 64 + lane;
      int row = idx / 28, j = idx % 28;
      uint4 v = make_uint4(0u, 0u, 0u, 0u);
      if (row < 12) v = reinterpret_cast<const uint4*>(DWtp + row * 224)[j];
      reinterpret_cast<uint4*>(&Bs[row * 232])[j] = v;
    }
    __syncthreads();
    f32x4 acc[4] = {};
    #pragma unroll
    for (int ks = 0; ks < 7; ++ks) {
      half8 bb = *reinterpret_cast<const half8*>(&Bs[r15 * 232 + ks * 32 + g8 * 8]);
      #pragma unroll
      for (int g = 0; g < 4; ++g) {
        half8 a = *reinterpret_cast<const half8*>(&As[(g * 16 + r15) * 232 + ks * 32 + g8 * 8]);
        acc[g] = mfma16(a, bb, acc[g]);
      }
    }
    if (r15 < 12) {
      float bv = biasT[r15];
      #pragma unroll
      for (int g = 0; g < 4; ++g) {
        #pragma unroll
        for (int q = 0; q < 4; ++q) {
          int r = mt * 64 + g * 16 + g8 * 4 + q;
          Bt_ws[((r >> 8) * 12 + r15) * 256 + (r & 255)] = acc[g][q] + bv;
        }
      }
    }
  } else { // E[o][p] = sum_s DWs[o,s]*se[p,s]
    int t2 = (bid - 672) * 64 + lane;
    if (t2 < 360) {
      int o = t2 / 30, p = t2 % 30;
      float acc = 0.f;
      #pragma unroll
      for (int s = 0; s < 25; ++s) acc += DWs[o * 25 + s] * se[p * 25 + s];
      E[t2] = acc;
    }
  }
}

// ---------------- main: out[b,o,m,n] = P(m,:)·tail(n,:) + A[m] + Bt[n] + E[span] + db ----------------
__global__ void __launch_bounds__(64) k_main(
    const unsigned short* __restrict__ P16, const unsigned short* __restrict__ tail16,
    const float* __restrict__ A_ws, const float* __restrict__ Bt_ws,
    const float* __restrict__ E, const float* __restrict__ db,
    float* __restrict__ out)
{
  __shared__ __align__(16) unsigned short Ps[64 * 232];
  __shared__ __align__(16) unsigned short Ts[64 * 232];
  int bid = blockIdx.x;
  int nt = bid & 3, mt = (bid >> 2) & 3, bo = bid >> 4;
  int o = bo % 12, b = bo / 12;
  int lane = threadIdx.x, r15 = lane & 15, g8 = lane >> 4;
  {
    const uint4* s = reinterpret_cast<const uint4*>(P16 + ((b * 256 + mt * 64 + lane) * 12 + o) * 224);
    uint4* d = reinterpret_cast<uint4*>(&Ps[lane * 232]);
    #pragma unroll
    for (int j = 0; j < 28; ++j) d[j] = s[j];
    const uint4* s2 = reinterpret_cast<const uint4*>(tail16 + (b * 256 + nt * 64 + lane) * 224);
    uint4* d2 = reinterpret_cast<uint4*>(&Ts[lane * 232]);
    #pragma unroll
    for (int j = 0; j < 28; ++j) d2[j] = s2[j];
  }
  __syncthreads();
  f32x4 acc[4][4] = {};
  #pragma unroll
  for (int ks = 0; ks < 7; ++ks) {
    half8 a[4], bb[4];
    #pragma unroll
    for (int g = 0; g < 4; ++g)
      a[g] = *reinterpret_cast<const half8*>(&Ps[(g * 16 + r15) * 232 + ks * 32 + g8 * 8]);
    #pragma unroll
    for (int h = 0; h < 4; ++h)
      bb[h] = *reinterpret_cast<const half8*>(&Ts[(h * 16 + r15) * 232 + ks * 32 + g8 * 8]);
    #pragma unroll
    for (int g = 0; g < 4; ++g) {
      #pragma unroll
      for (int h = 0; h < 4; ++h)
        acc[g][h] = mfma16(a[g], bb[h], acc[g][h]);
    }
  }
  const float dbv = db[o];
  const float* Arow = A_ws + (b * 12 + o) * 256;
  const float* Btrow = Bt_ws + (b * 12 + o) * 256;
  const float* Erow = E + o * 30;
  #pragma unroll
  for (int g = 0; g < 4; ++g) {
    #pragma unroll
    for (int q = 0; q < 4; ++q) {
      int m = mt * 64 + g * 16 + g8 * 4 + q;
      float am = Arow[m] + dbv;
      #pragma unroll
      for (int h = 0; h < 4; ++h) {
        int n = nt * 64 + h * 16 + r15;
        int dpos = n - m;
        dpos = (dpos < -15) ? -15 : (dpos > 14 ? 14 : dpos);
        out[((b * 12 + o) * 256 + m) * 256 + n] = acc[g][h][q] + am + Btrow[n] + Erow[dpos + 15];
      }
    }
  }
}

extern "C" void kernel_launch(void* const* d_in, const int* in_sizes, int n_in,
                              void* d_out, int out_size, void* d_ws, size_t ws_size,
                              hipStream_t stream) {
  (void)in_sizes; (void)n_in; (void)out_size; (void)ws_size;
  const float* wr = (const float*)d_in[0];
  const float* hw = (const float*)d_in[4];
  const float* hb = (const float*)d_in[5];
  const float* tw = (const float*)d_in[6];
  const float* tb = (const float*)d_in[7];
  const float* U  = (const float*)d_in[8];
  const float* se = (const float*)d_in[9];
  const float* W  = (const float*)d_in[10];
  const float* dw = (const float*)d_in[11];
  const float* db = (const float*)d_in[12];

  char* ws = (char*)d_ws;
  unsigned short* wr16   = (unsigned short*)(ws + 0);        // 1,572,864 B
  unsigned short* hw16   = (unsigned short*)(ws + 1572864);  //   307,200
  unsigned short* tw16   = (unsigned short*)(ws + 1880064);  //   307,200
  unsigned short* headp  = (unsigned short*)(ws + 2187264);  //   655,360  [1024][320]
  unsigned short* tail16 = (unsigned short*)(ws + 2842624);  //   458,752  [1024][224]
  unsigned short* P16    = (unsigned short*)(ws + 3301376);  // 5,505,024  [1024*12][224]
  float* A_ws            = (float*)(ws + 8806400);           //    49,152
  float* Bt_ws           = (float*)(ws + 8855552);           //    49,152
  unsigned short* DWhp   = (unsigned short*)(ws + 8904704);  //     7,680
  unsigned short* DWtp   = (unsigned short*)(ws + 8912384);  //     5,376
  float* biasH           = (float*)(ws + 8917760);           //        64
  float* biasT           = (float*)(ws + 8917824);           //        64
  float* E_ws            = (float*)(ws + 8917888);           //     1,440
  float* DWs             = (float*)(ws + 8919328);           //     1,200
  unsigned short* Gp     = (unsigned short*)(ws + 8920528);  //   307,200  -> end ~9.23 MB

  kA<<<1697, 256, 0, stream>>>(wr, hw, tw, U, W, dw,
                               wr16, hw16, tw16, headp, tail16, P16,
                               DWhp, DWtp, biasH, biasT, DWs, Gp);
  k_gemm1<<<112, 64, 0, stream>>>(wr16, hw16, tw16, hb, tb, headp, tail16);
  k_gemm2<<<678, 64, 0, stream>>>(headp, tail16, Gp, DWhp, DWtp, biasH, biasT,
                                  se, DWs, P16, A_ws, Bt_ws, E_ws);
  k_main<<<768, 64, 0, stream>>>(P16, tail16, A_ws, Bt_ws, E_ws, db,
                                 (float*)d_out);
}

// Round 8
// 55.124 us; speedup vs baseline: 1.5210x; 1.0612x over previous
//
#include <hip/hip_runtime.h>

typedef _Float16 half8 __attribute__((ext_vector_type(8)));
typedef __fp16   fp16x2 __attribute__((ext_vector_type(2)));
typedef float    f32x4 __attribute__((ext_vector_type(4)));

#define DEV static __device__ __forceinline__

DEV unsigned short f2h(float f) {
  _Float16 h = (_Float16)f;
  return __builtin_bit_cast(unsigned short, h);
}
DEV float lrelu(float x) { return x > 0.f ? x : 0.01f * x; }
DEV f32x4 mfma16(half8 a, half8 b, f32x4 c) {
  return __builtin_amdgcn_mfma_f32_16x16x32_f16(a, b, c, 0, 0, 0);
}
DEV uint2 pk4(float4 v) {
  fp16x2 a = __builtin_amdgcn_cvt_pkrtz(v.x, v.y);
  fp16x2 b = __builtin_amdgcn_cvt_pkrtz(v.z, v.w);
  return make_uint2(__builtin_bit_cast(unsigned, a), __builtin_bit_cast(unsigned, b));
}

// dims: B=4 N=256 H=768 D=200 NH=5 HD=40 OUT=12
// padded K: head 320 (5*64), tail/P 224. Inputs f32, output f32.

// ================= K1: gemm1 (f32->f16 in staging) + DW + G + pads =================
// blocks [0,112): gemm1 | [112,540): DW col | [540,665): G | [665,1069): pads
__global__ void __launch_bounds__(64) k1(
    const float* __restrict__ wr, const float* __restrict__ hw,
    const float* __restrict__ tw, const float* __restrict__ hb,
    const float* __restrict__ tb, const float* __restrict__ U,
    const float* __restrict__ W, const float* __restrict__ dw,
    unsigned short* __restrict__ headp, unsigned short* __restrict__ tail16,
    unsigned short* __restrict__ DWhp, unsigned short* __restrict__ DWtp,
    float* __restrict__ biasH, float* __restrict__ biasT,
    float* __restrict__ DWs, unsigned short* __restrict__ Gp)
{
  int bid = blockIdx.x;
  int lane = threadIdx.x;
  if (bid < 112) {
    // ---- GEMM1: [1024x768] x [400x768]^T -> leaky_relu -> headp/tail16
    __shared__ __align__(16) unsigned short Xs[64 * 136];
    __shared__ __align__(16) unsigned short Wsh[64 * 136];
    int mt = bid / 7, nt = bid % 7;
    int r15 = lane & 15, g8 = lane >> 4;
    int rb = mt * 64, cb = nt * 64;
    int c = cb + lane;

    f32x4 acc[4][4] = {};
    for (int kt = 0; kt < 6; ++kt) {
      int k0 = kt * 128;
      {
        const float4* s = reinterpret_cast<const float4*>(wr + (rb + lane) * 768 + k0);
        uint4* d = reinterpret_cast<uint4*>(&Xs[lane * 136]);
        #pragma unroll
        for (int j = 0; j < 16; ++j) {
          uint2 pa = pk4(s[2 * j]), pb = pk4(s[2 * j + 1]);
          d[j] = make_uint4(pa.x, pa.y, pb.x, pb.y);
        }
      }
      {
        uint4* d = reinterpret_cast<uint4*>(&Wsh[lane * 136]);
        if (c < 400) {
          const float4* s = reinterpret_cast<const float4*>(
              (c < 200 ? hw + c * 768 : tw + (c - 200) * 768) + k0);
          #pragma unroll
          for (int j = 0; j < 16; ++j) {
            uint2 pa = pk4(s[2 * j]), pb = pk4(s[2 * j + 1]);
            d[j] = make_uint4(pa.x, pa.y, pb.x, pb.y);
          }
        } else {
          uint4 z = make_uint4(0u, 0u, 0u, 0u);
          #pragma unroll
          for (int j = 0; j < 16; ++j) d[j] = z;
        }
      }
      __syncthreads();
      #pragma unroll
      for (int ks = 0; ks < 4; ++ks) {
        half8 a[4], bb[4];
        #pragma unroll
        for (int g = 0; g < 4; ++g)
          a[g] = *reinterpret_cast<const half8*>(&Xs[(g * 16 + r15) * 136 + ks * 32 + g8 * 8]);
        #pragma unroll
        for (int h = 0; h < 4; ++h)
          bb[h] = *reinterpret_cast<const half8*>(&Wsh[(h * 16 + r15) * 136 + ks * 32 + g8 * 8]);
        #pragma unroll
        for (int g = 0; g < 4; ++g) {
          #pragma unroll
          for (int h = 0; h < 4; ++h)
            acc[g][h] = mfma16(a[g], bb[h], acc[g][h]);
        }
      }
      __syncthreads();
    }
    #pragma unroll
    for (int h = 0; h < 4; ++h) {
      int cc = cb + h * 16 + r15;
      if (cc >= 400) continue;
      float bias = (cc < 200) ? hb[cc] : tb[cc - 200];
      #pragma unroll
      for (int g = 0; g < 4; ++g) {
        #pragma unroll
        for (int q = 0; q < 4; ++q) {
          int m = rb + g * 16 + g8 * 4 + q;
          float val = lrelu(acc[g][h][q] + bias);
          if (cc < 200) headp[m * 320 + (cc / 40) * 64 + (cc % 40)] = f2h(val);
          else          tail16[m * 224 + (cc - 200)] = f2h(val);
        }
      }
    }
    return;
  }
  if (bid < 540) {  // ---- DW: wave-per-column, coalesced W rows + dw direct
    int col = bid - 112;
    if (col >= 427) return;
    float wv0 = W[lane * 427 + col];
    float wv1 = W[(lane + 64) * 427 + col];
    float wv2 = W[(lane + 128) * 427 + col];
    float wv3 = (lane < 8) ? W[(lane + 192) * 427 + col] : 0.f;
    float acc[12];
    #pragma unroll
    for (int o = 0; o < 12; ++o) {
      const float* dr = dw + o * 200;
      float a = dr[lane] * wv0 + dr[lane + 64] * wv1 + dr[lane + 128] * wv2;
      if (lane < 8) a += dr[lane + 192] * wv3;
      acc[o] = a;
    }
    #pragma unroll
    for (int s = 1; s < 64; s <<= 1) {
      #pragma unroll
      for (int o = 0; o < 12; ++o) acc[o] += __shfl_xor(acc[o], s, 64);
    }
    if (lane == 0) {
      if (col < 200) {
        int h = col / 40, x = col % 40;
        #pragma unroll
        for (int o = 0; o < 12; ++o) DWhp[o * 320 + h * 64 + x] = f2h(acc[o]);
      } else if (col == 200) {
        #pragma unroll
        for (int o = 0; o < 12; ++o) biasH[o] = acc[o];
      } else if (col < 401) {
        int k = col - 201;
        #pragma unroll
        for (int o = 0; o < 12; ++o) DWtp[o * 224 + k] = f2h(acc[o]);
      } else if (col == 401) {
        #pragma unroll
        for (int o = 0; o < 12; ++o) biasT[o] = acc[o];
      } else {
        int s = col - 402;
        #pragma unroll
        for (int o = 0; o < 12; ++o) DWs[o * 25 + s] = acc[o];
      }
    }
    return;
  }
  if (bid < 665) {  // ---- G: thread-per-(h,x,y); h uniform per block
    __shared__ float dws40[480];
    int t = (bid - 540) * 64 + lane;
    int h = t / 1600, r = t % 1600, x = r / 40, y = r % 40;
    for (int i = lane; i < 480; i += 64)
      dws40[i] = dw[(i / 40) * 200 + h * 40 + (i % 40)];
    __syncthreads();
    const float* Ub = U + ((h * 40) * 40 + x) * 40 + y;
    float acc[12] = {};
    #pragma unroll 4
    for (int d = 0; d < 40; ++d) {
      float uv = Ub[d * 1600];
      #pragma unroll
      for (int o = 0; o < 12; ++o) acc[o] += dws40[o * 40 + d] * uv;
    }
    #pragma unroll
    for (int o = 0; o < 12; ++o)
      Gp[(h * 480 + o * 40 + y) * 64 + x] = f2h(acc[o]);
    return;
  }
  {  // ---- pads (uint4 = 8 f16 zeros each)
    int p = (bid - 665) * 64 + lane;
    uint4 z = make_uint4(0u, 0u, 0u, 0u);
    if (p < 3072) {            // tail16 [200,224)
      int row = p / 3, j = p % 3;
      *reinterpret_cast<uint4*>(tail16 + row * 224 + 200 + j * 8) = z;
      return;
    }
    p -= 3072;
    if (p < 15360) {           // headp [40,64) per group
      int row = p / 15, rem = p % 15, h = rem / 3, j = rem % 3;
      *reinterpret_cast<uint4*>(headp + row * 320 + h * 64 + 40 + j * 8) = z;
      return;
    }
    p -= 15360;
    if (p < 7200) {            // Gp [40,64)
      int row = p / 3, j = p % 3;
      *reinterpret_cast<uint4*>(Gp + row * 64 + 40 + j * 8) = z;
      return;
    }
    p -= 7200;
    if (p < 180) {             // DWhp [40,64)
      int ro = p / 3, j = p % 3, o = ro / 5, h = ro % 5;
      *reinterpret_cast<uint4*>(DWhp + o * 320 + h * 64 + 40 + j * 8) = z;
      return;
    }
    p -= 180;
    if (p < 36) {              // DWtp [200,224)
      int o = p / 3, j = p % 3;
      *reinterpret_cast<uint4*>(DWtp + o * 224 + 200 + j * 8) = z;
      return;
    }
    return;
  }
}

// ================= K2: P (h,mt blocks, LDS A-tile) + A + Bt + E =================
__global__ void __launch_bounds__(256) k2(
    const unsigned short* __restrict__ headp, const unsigned short* __restrict__ tail16,
    const unsigned short* __restrict__ Gp, const unsigned short* __restrict__ DWhp,
    const unsigned short* __restrict__ DWtp, const float* __restrict__ biasH,
    const float* __restrict__ biasT, const float* __restrict__ se,
    const float* __restrict__ DWs, unsigned short* __restrict__ P16,
    float* __restrict__ A_ws, float* __restrict__ Bt_ws, float* __restrict__ E)
{
  int bid = blockIdx.x, tid = threadIdx.x;
  int wid = tid >> 6, lane = tid & 63, r15 = lane & 15, g8 = lane >> 4;

  if (bid < 80) { // ---- P: h = bid/16, mt = bid%16; 4 waves x 2 nt each
    __shared__ __align__(16) unsigned short As[64 * 72];
    int h = bid / 16, mt = bid % 16;
    // stage A-tile: 64 rows x 64 k (f16) of headp group h
    #pragma unroll
    for (int i = 0; i < 2; ++i) {
      int idx = i * 256 + tid;          // 512 uint4
      int row = idx / 8, j = idx % 8;
      *reinterpret_cast<uint4*>(&As[row * 72 + j * 8]) =
          reinterpret_cast<const uint4*>(headp + (mt * 64 + row) * 320 + h * 64)[j];
    }
    __syncthreads();
    #pragma unroll
    for (int rep = 0; rep < 2; ++rep) {
      int nt = wid * 2 + rep;           // 0..7
      const uint4* bptr[4];
      #pragma unroll
      for (int hh = 0; hh < 4; ++hh) {
        int cc = nt * 64 + hh * 16 + r15;
        int rcl = cc < 479 ? cc : 479;
        bptr[hh] = reinterpret_cast<const uint4*>(Gp + (h * 480 + rcl) * 64);
      }
      f32x4 acc[4][4] = {};
      #pragma unroll
      for (int ks = 0; ks < 2; ++ks) {
        int idx = ks * 4 + g8;
        half8 a[4], bb[4];
        #pragma unroll
        for (int g = 0; g < 4; ++g)
          a[g] = *reinterpret_cast<const half8*>(&As[(g * 16 + r15) * 72 + ks * 32 + g8 * 8]);
        #pragma unroll
        for (int hh = 0; hh < 4; ++hh) bb[hh] = __builtin_bit_cast(half8, bptr[hh][idx]);
        #pragma unroll
        for (int g = 0; g < 4; ++g) {
          #pragma unroll
          for (int hh = 0; hh < 4; ++hh)
            acc[g][hh] = mfma16(a[g], bb[hh], acc[g][hh]);
        }
      }
      #pragma unroll
      for (int hh = 0; hh < 4; ++hh) {
        int cc = nt * 64 + hh * 16 + r15;
        if (cc >= 480) continue;
        int o = cc / 40, y = cc % 40;
        #pragma unroll
        for (int g = 0; g < 4; ++g) {
          #pragma unroll
          for (int q = 0; q < 4; ++q) {
            int r = mt * 64 + g * 16 + g8 * 4 + q;
            int rowb = (r * 12 + o) * 224;
            P16[rowb + h * 40 + y] = f2h(acc[g][hh][q]);
            if (h == 4 && y < 24) P16[rowb + 200 + y] = 0;  // k-pad zeros
          }
        }
      }
    }
  } else if (bid < 84) { // ---- A: [1024x320] x DWhp[12(16)x320]^T (direct global)
    int mt = (bid - 80) * 4 + wid;
    const uint4* aptr[4];
    #pragma unroll
    for (int g = 0; g < 4; ++g)
      aptr[g] = reinterpret_cast<const uint4*>(headp + (mt * 64 + g * 16 + r15) * 320);
    int brow = r15 < 11 ? r15 : 11;
    const uint4* bptr = reinterpret_cast<const uint4*>(DWhp + brow * 320);
    f32x4 acc[4] = {};
    #pragma unroll
    for (int ks = 0; ks < 10; ++ks) {
      int idx = ks * 4 + g8;
      half8 bb = __builtin_bit_cast(half8, bptr[idx]);
      #pragma unroll
      for (int g = 0; g < 4; ++g) {
        half8 a = __builtin_bit_cast(half8, aptr[g][idx]);
        acc[g] = mfma16(a, bb, acc[g]);
      }
    }
    if (r15 < 12) {
      float bv = biasH[r15];
      #pragma unroll
      for (int g = 0; g < 4; ++g) {
        #pragma unroll
        for (int q = 0; q < 4; ++q) {
          int r = mt * 64 + g * 16 + g8 * 4 + q;
          A_ws[((r >> 8) * 12 + r15) * 256 + (r & 255)] = acc[g][q] + bv;
        }
      }
    }
  } else if (bid < 88) { // ---- Bt: [1024x224] x DWtp[12(16)x224]^T
    int mt = (bid - 84) * 4 + wid;
    const uint4* aptr[4];
    #pragma unroll
    for (int g = 0; g < 4; ++g)
      aptr[g] = reinterpret_cast<const uint4*>(tail16 + (mt * 64 + g * 16 + r15) * 224);
    int brow = r15 < 11 ? r15 : 11;
    const uint4* bptr = reinterpret_cast<const uint4*>(DWtp + brow * 224);
    f32x4 acc[4] = {};
    #pragma unroll
    for (int ks = 0; ks < 7; ++ks) {
      int idx = ks * 4 + g8;
      half8 bb = __builtin_bit_cast(half8, bptr[idx]);
      #pragma unroll
      for (int g = 0; g < 4; ++g) {
        half8 a = __builtin_bit_cast(half8, aptr[g][idx]);
        acc[g] = mfma16(a, bb, acc[g]);
      }
    }
    if (r15 < 12) {
      float bv = biasT[r15];
      #pragma unroll
      for (int g = 0; g < 4; ++g) {
        #pragma unroll
        for (int q = 0; q < 4; ++q) {
          int r = mt * 64 + g * 16 + g8 * 4 + q;
          Bt_ws[((r >> 8) * 12 + r15) * 256 + (r & 255)] = acc[g][q] + bv;
        }
      }
    }
  } else { // ---- E[o][p]
    int t2 = (bid - 88) * 256 + tid;
    if (t2 < 360) {
      int o = t2 / 30, pp = t2 % 30;
      float acc = 0.f;
      #pragma unroll
      for (int s = 0; s < 25; ++s) acc += DWs[o * 25 + s] * se[pp * 25 + s];
      E[t2] = acc;
    }
  }
}

// ================= K3: main — (b,o,mt) blocks, P-tile LDS, T direct =================
__global__ void __launch_bounds__(256) k3(
    const unsigned short* __restrict__ P16, const unsigned short* __restrict__ tail16,
    const float* __restrict__ A_ws, const float* __restrict__ Bt_ws,
    const float* __restrict__ E, const float* __restrict__ db,
    float* __restrict__ out)
{
  __shared__ __align__(16) unsigned short Ps[64 * 232];
  int bid = blockIdx.x, tid = threadIdx.x;
  int mt = bid & 3, ob = bid >> 2;
  int o = ob % 12, b = ob / 12;
  int wid = tid >> 6, lane = tid & 63, r15 = lane & 15, g8 = lane >> 4;

  // stage P-tile: 64 rows x 224 k (f16)
  #pragma unroll
  for (int i = 0; i < 7; ++i) {
    int idx = i * 256 + tid;            // 1792 uint4
    int row = idx / 28, j = idx % 28;
    *reinterpret_cast<uint4*>(&Ps[row * 232 + j * 8]) =
        reinterpret_cast<const uint4*>(P16 + ((b * 256 + mt * 64 + row) * 12 + o) * 224)[j];
  }
  __syncthreads();

  int nt = wid;
  const uint4* bptr[4];
  #pragma unroll
  for (int h = 0; h < 4; ++h)
    bptr[h] = reinterpret_cast<const uint4*>(
        tail16 + (b * 256 + nt * 64 + h * 16 + r15) * 224);

  f32x4 acc[4][4] = {};
  #pragma unroll
  for (int ks = 0; ks < 7; ++ks) {
    int idx = ks * 4 + g8;
    half8 a[4], bb[4];
    #pragma unroll
    for (int g = 0; g < 4; ++g)
      a[g] = *reinterpret_cast<const half8*>(&Ps[(g * 16 + r15) * 232 + ks * 32 + g8 * 8]);
    #pragma unroll
    for (int h = 0; h < 4; ++h) bb[h] = __builtin_bit_cast(half8, bptr[h][idx]);
    #pragma unroll
    for (int g = 0; g < 4; ++g) {
      #pragma unroll
      for (int h = 0; h < 4; ++h)
        acc[g][h] = mfma16(a[g], bb[h], acc[g][h]);
    }
  }
  const float dbv = db[o];
  const float* Arow = A_ws + (b * 12 + o) * 256;
  const float* Btrow = Bt_ws + (b * 12 + o) * 256;
  const float* Erow = E + o * 30;
  #pragma unroll
  for (int g = 0; g < 4; ++g) {
    #pragma unroll
    for (int q = 0; q < 4; ++q) {
      int m = mt * 64 + g * 16 + g8 * 4 + q;
      float am = Arow[m] + dbv;
      #pragma unroll
      for (int h = 0; h < 4; ++h) {
        int n = nt * 64 + h * 16 + r15;
        int dpos = n - m;
        dpos = (dpos < -15) ? -15 : (dpos > 14 ? 14 : dpos);
        out[((b * 12 + o) * 256 + m) * 256 + n] = acc[g][h][q] + am + Btrow[n] + Erow[dpos + 15];
      }
    }
  }
}

extern "C" void kernel_launch(void* const* d_in, const int* in_sizes, int n_in,
                              void* d_out, int out_size, void* d_ws, size_t ws_size,
                              hipStream_t stream) {
  (void)in_sizes; (void)n_in; (void)out_size; (void)ws_size;
  const float* wr = (const float*)d_in[0];
  const float* hw = (const float*)d_in[4];
  const float* hb = (const float*)d_in[5];
  const float* tw = (const float*)d_in[6];
  const float* tb = (const float*)d_in[7];
  const float* U  = (const float*)d_in[8];
  const float* se = (const float*)d_in[9];
  const float* W  = (const float*)d_in[10];
  const float* dw = (const float*)d_in[11];
  const float* db = (const float*)d_in[12];

  char* ws = (char*)d_ws;
  unsigned short* headp  = (unsigned short*)(ws + 0);        //   655,360  [1024][320]
  unsigned short* tail16 = (unsigned short*)(ws + 655360);   //   458,752  [1024][224]
  unsigned short* P16    = (unsigned short*)(ws + 1114112);  // 5,505,024  [1024*12][224]
  float* A_ws            = (float*)(ws + 6619136);           //    49,152
  float* Bt_ws           = (float*)(ws + 6668288);           //    49,152
  unsigned short* DWhp   = (unsigned short*)(ws + 6717440);  //     7,680
  unsigned short* DWtp   = (unsigned short*)(ws + 6725120);  //     5,376
  float* biasH           = (float*)(ws + 6730496);           //        64
  float* biasT           = (float*)(ws + 6730560);           //        64
  float* E_ws            = (float*)(ws + 6730624);           //     1,440
  float* DWs             = (float*)(ws + 6732064);           //     1,200
  unsigned short* Gp     = (unsigned short*)(ws + 6733264);  //   307,200  -> end ~7.04 MB

  k1<<<1069, 64, 0, stream>>>(wr, hw, tw, hb, tb, U, W, dw,
                              headp, tail16, DWhp, DWtp, biasH, biasT, DWs, Gp);
  k2<<<90, 256, 0, stream>>>(headp, tail16, Gp, DWhp, DWtp, biasH, biasT,
                             se, DWs, P16, A_ws, Bt_ws, E_ws);
  k3<<<192, 256, 0, stream>>>(P16, tail16, A_ws, Bt_ws, E_ws, db, (float*)d_out);
}

// Round 9
// 48.024 us; speedup vs baseline: 1.7459x; 1.1478x over previous
//
#include <hip/hip_runtime.h>

typedef _Float16 half8 __attribute__((ext_vector_type(8)));
typedef __fp16   fp16x2 __attribute__((ext_vector_type(2)));
typedef float    f32x4 __attribute__((ext_vector_type(4)));

#define DEV static __device__ __forceinline__

DEV unsigned short f2h(float f) {
  _Float16 h = (_Float16)f;
  return __builtin_bit_cast(unsigned short, h);
}
DEV float h2f(unsigned short u) { return (float)__builtin_bit_cast(_Float16, u); }
DEV float lrelu(float x) { return x > 0.f ? x : 0.01f * x; }
DEV f32x4 mfma16(half8 a, half8 b, f32x4 c) {
  return __builtin_amdgcn_mfma_f32_16x16x32_f16(a, b, c, 0, 0, 0);
}
DEV uint2 pk4(float4 v) {
  fp16x2 a = __builtin_amdgcn_cvt_pkrtz(v.x, v.y);
  fp16x2 b = __builtin_amdgcn_cvt_pkrtz(v.z, v.w);
  return make_uint2(__builtin_bit_cast(unsigned, a), __builtin_bit_cast(unsigned, b));
}

// dims: B=4 N=256 H=768 D=200 NH=5 HD=40 OUT=12
// Inputs f32, output f32. Epilogue algebra folded into the main GEMM:
//   Bt  -> add DWt[o] to every P row
//   A + biasH + biasT + db -> P col 200, with tail16[n][200] = 1.0
//   E[span] -> only remaining epilogue add

// ================= K1: gemm1 + DW + G + E + pads =================
// blocks [0,112): gemm1 | [112,514): DW col | [514,639): G | [639,999): E | [999,1403): pads
__global__ void __launch_bounds__(64) k1(
    const float* __restrict__ wr, const float* __restrict__ hw,
    const float* __restrict__ tw, const float* __restrict__ hb,
    const float* __restrict__ tb, const float* __restrict__ U,
    const float* __restrict__ W, const float* __restrict__ dw,
    const float* __restrict__ se,
    unsigned short* __restrict__ headp, unsigned short* __restrict__ tail16,
    unsigned short* __restrict__ DWhp, unsigned short* __restrict__ DWtp,
    float* __restrict__ biasH, float* __restrict__ biasT,
    float* __restrict__ E, unsigned short* __restrict__ Gp)
{
  int bid = blockIdx.x;
  int lane = threadIdx.x;
  if (bid < 112) {
    // ---- GEMM1: [1024x768] x [400x768]^T -> leaky_relu -> headp/tail16
    __shared__ __align__(16) unsigned short Xs[64 * 136];
    __shared__ __align__(16) unsigned short Wsh[64 * 136];
    int mt = bid / 7, nt = bid % 7;
    int r15 = lane & 15, g8 = lane >> 4;
    int rb = mt * 64, cb = nt * 64;
    int c = cb + lane;

    f32x4 acc[4][4] = {};
    for (int kt = 0; kt < 6; ++kt) {
      int k0 = kt * 128;
      {
        const float4* s = reinterpret_cast<const float4*>(wr + (rb + lane) * 768 + k0);
        uint4* d = reinterpret_cast<uint4*>(&Xs[lane * 136]);
        #pragma unroll
        for (int j = 0; j < 16; ++j) {
          uint2 pa = pk4(s[2 * j]), pb = pk4(s[2 * j + 1]);
          d[j] = make_uint4(pa.x, pa.y, pb.x, pb.y);
        }
      }
      {
        uint4* d = reinterpret_cast<uint4*>(&Wsh[lane * 136]);
        if (c < 400) {
          const float4* s = reinterpret_cast<const float4*>(
              (c < 200 ? hw + c * 768 : tw + (c - 200) * 768) + k0);
          #pragma unroll
          for (int j = 0; j < 16; ++j) {
            uint2 pa = pk4(s[2 * j]), pb = pk4(s[2 * j + 1]);
            d[j] = make_uint4(pa.x, pa.y, pb.x, pb.y);
          }
        } else {
          uint4 z = make_uint4(0u, 0u, 0u, 0u);
          #pragma unroll
          for (int j = 0; j < 16; ++j) d[j] = z;
        }
      }
      __syncthreads();
      #pragma unroll
      for (int ks = 0; ks < 4; ++ks) {
        half8 a[4], bb[4];
        #pragma unroll
        for (int g = 0; g < 4; ++g)
          a[g] = *reinterpret_cast<const half8*>(&Xs[(g * 16 + r15) * 136 + ks * 32 + g8 * 8]);
        #pragma unroll
        for (int h = 0; h < 4; ++h)
          bb[h] = *reinterpret_cast<const half8*>(&Wsh[(h * 16 + r15) * 136 + ks * 32 + g8 * 8]);
        #pragma unroll
        for (int g = 0; g < 4; ++g) {
          #pragma unroll
          for (int h = 0; h < 4; ++h)
            acc[g][h] = mfma16(a[g], bb[h], acc[g][h]);
        }
      }
      __syncthreads();
    }
    #pragma unroll
    for (int h = 0; h < 4; ++h) {
      int cc = cb + h * 16 + r15;
      if (cc >= 400) continue;
      float bias = (cc < 200) ? hb[cc] : tb[cc - 200];
      #pragma unroll
      for (int g = 0; g < 4; ++g) {
        #pragma unroll
        for (int q = 0; q < 4; ++q) {
          int m = rb + g * 16 + g8 * 4 + q;
          float val = lrelu(acc[g][h][q] + bias);
          if (cc < 200) headp[m * 320 + (cc / 40) * 64 + (cc % 40)] = f2h(val);
          else          tail16[m * 224 + (cc - 200)] = f2h(val);
        }
      }
    }
    return;
  }
  if (bid < 514) {  // ---- DW: wave-per-column (cols 0..401), coalesced W rows
    int col = bid - 112;
    float wv0 = W[lane * 427 + col];
    float wv1 = W[(lane + 64) * 427 + col];
    float wv2 = W[(lane + 128) * 427 + col];
    float wv3 = (lane < 8) ? W[(lane + 192) * 427 + col] : 0.f;
    float acc[12];
    #pragma unroll
    for (int o = 0; o < 12; ++o) {
      const float* dr = dw + o * 200;
      float a = dr[lane] * wv0 + dr[lane + 64] * wv1 + dr[lane + 128] * wv2;
      if (lane < 8) a += dr[lane + 192] * wv3;
      acc[o] = a;
    }
    #pragma unroll
    for (int s = 1; s < 64; s <<= 1) {
      #pragma unroll
      for (int o = 0; o < 12; ++o) acc[o] += __shfl_xor(acc[o], s, 64);
    }
    if (lane == 0) {
      if (col < 200) {
        int h = col / 40, x = col % 40;
        #pragma unroll
        for (int o = 0; o < 12; ++o) DWhp[o * 320 + h * 64 + x] = f2h(acc[o]);
      } else if (col == 200) {
        #pragma unroll
        for (int o = 0; o < 12; ++o) biasH[o] = acc[o];
      } else if (col < 401) {
        int k = col - 201;
        #pragma unroll
        for (int o = 0; o < 12; ++o) DWtp[o * 224 + k] = f2h(acc[o]);
      } else {
        #pragma unroll
        for (int o = 0; o < 12; ++o) biasT[o] = acc[o];
      }
    }
    return;
  }
  if (bid < 639) {  // ---- G: thread-per-(h,x,y); h uniform per block
    __shared__ float dws40[480];
    int t = (bid - 514) * 64 + lane;
    int h = t / 1600, r = t % 1600, x = r / 40, y = r % 40;
    for (int i = lane; i < 480; i += 64)
      dws40[i] = dw[(i / 40) * 200 + h * 40 + (i % 40)];
    __syncthreads();
    const float* Ub = U + ((h * 40) * 40 + x) * 40 + y;
    float acc[12] = {};
    #pragma unroll 4
    for (int d = 0; d < 40; ++d) {
      float uv = Ub[d * 1600];
      #pragma unroll
      for (int o = 0; o < 12; ++o) acc[o] += dws40[o * 40 + d] * uv;
    }
    #pragma unroll
    for (int o = 0; o < 12; ++o)
      Gp[(h * 480 + o * 40 + y) * 64 + x] = f2h(acc[o]);
    return;
  }
  if (bid < 999) {  // ---- E: block per (o,p); E[o][p] = sum_kk dw[o,kk]*(sum_s W[kk,402+s]*se[p,s])
    int e = bid - 639;
    int o = e / 30, p = e % 30;
    float sev[25];
    #pragma unroll
    for (int s = 0; s < 25; ++s) sev[s] = se[p * 25 + s];
    float v = 0.f;
    for (int kk = lane; kk < 200; kk += 64) {
      const float* wrow = W + kk * 427 + 402;
      float wse = 0.f;
      #pragma unroll
      for (int s = 0; s < 25; ++s) wse += wrow[s] * sev[s];
      v += dw[o * 200 + kk] * wse;
    }
    #pragma unroll
    for (int s = 1; s < 64; s <<= 1) v += __shfl_xor(v, s, 64);
    if (lane == 0) E[o * 30 + p] = v;
    return;
  }
  {  // ---- pads
    int p = (bid - 999) * 64 + lane;
    uint4 z = make_uint4(0u, 0u, 0u, 0u);
    if (p < 3072) {            // tail16 [200,224): col200 = 1.0f16, rest 0
      int row = p / 3, j = p % 3;
      uint4 v = (j == 0) ? make_uint4(0x00003C00u, 0u, 0u, 0u) : z;
      *reinterpret_cast<uint4*>(tail16 + row * 224 + 200 + j * 8) = v;
      return;
    }
    p -= 3072;
    if (p < 15360) {           // headp [40,64) per group
      int row = p / 15, rem = p % 15, h = rem / 3, j = rem % 3;
      *reinterpret_cast<uint4*>(headp + row * 320 + h * 64 + 40 + j * 8) = z;
      return;
    }
    p -= 15360;
    if (p < 7200) {            // Gp [40,64)
      int row = p / 3, j = p % 3;
      *reinterpret_cast<uint4*>(Gp + row * 64 + 40 + j * 8) = z;
      return;
    }
    p -= 7200;
    if (p < 180) {             // DWhp [40,64)
      int ro = p / 3, j = p % 3, o = ro / 5, h = ro % 5;
      *reinterpret_cast<uint4*>(DWhp + o * 320 + h * 64 + 40 + j * 8) = z;
      return;
    }
    return;
  }
}

// ================= K3: fused P + main GEMM per (b,o,mt) block =================
__global__ void __launch_bounds__(256) k3(
    const unsigned short* __restrict__ headp, const unsigned short* __restrict__ tail16,
    const unsigned short* __restrict__ Gp, const unsigned short* __restrict__ DWhp,
    const unsigned short* __restrict__ DWtp, const float* __restrict__ biasH,
    const float* __restrict__ biasT, const float* __restrict__ E,
    const float* __restrict__ db, float* __restrict__ out)
{
  __shared__ __align__(16) unsigned short Ps[64 * 232];
  int bid = blockIdx.x, tid = threadIdx.x;
  int mt = bid & 3, ob = bid >> 2;
  int o = ob % 12, b = ob / 12;
  int wid = tid >> 6, lane = tid & 63, r15 = lane & 15, g8 = lane >> 4;

  // zero P cols [201,224)
  for (int idx = tid; idx < 64 * 23; idx += 256)
    Ps[(idx / 23) * 232 + 201 + idx % 23] = 0;

  // ---- phase A: wave wid computes P rows [wid*16, wid*16+16)
  {
    const unsigned short* arow = headp + (b * 256 + mt * 64 + wid * 16 + r15) * 320;
    f32x4 accA = {};
    #pragma unroll
    for (int h = 0; h < 5; ++h) {
      f32x4 accY[3] = {};
      #pragma unroll
      for (int ks = 0; ks < 2; ++ks) {
        half8 av = *reinterpret_cast<const half8*>(arow + h * 64 + ks * 32 + g8 * 8);
        #pragma unroll
        for (int yf = 0; yf < 3; ++yf) {
          int yy = yf * 16 + r15;
          int yc = yy < 40 ? yy : 39;
          half8 bv = *reinterpret_cast<const half8*>(
              Gp + (h * 480 + o * 40 + yc) * 64 + ks * 32 + g8 * 8);
          accY[yf] = mfma16(av, bv, accY[yf]);
        }
        half8 bA = *reinterpret_cast<const half8*>(DWhp + o * 320 + h * 64 + ks * 32 + g8 * 8);
        accA = mfma16(av, bA, accA);
      }
      #pragma unroll
      for (int yf = 0; yf < 3; ++yf) {
        int yy = yf * 16 + r15;
        if (yy < 40) {
          int c = h * 40 + yy;
          float dwt = h2f(DWtp[o * 224 + c]);   // Bt fold
          #pragma unroll
          for (int q = 0; q < 4; ++q)
            Ps[(wid * 16 + g8 * 4 + q) * 232 + c] = f2h(accY[yf][q] + dwt);
        }
      }
    }
    if (r15 == 0) {
      float cst = biasH[o] + biasT[o] + db[o];
      #pragma unroll
      for (int q = 0; q < 4; ++q)
        Ps[(wid * 16 + g8 * 4 + q) * 232 + 200] = f2h(accA[q] + cst);  // A fold
    }
  }
  __syncthreads();

  // ---- phase B: main GEMM, wave wid owns output cols [wid*64, wid*64+64)
  int nt = wid;
  const uint4* bptr[4];
  #pragma unroll
  for (int h = 0; h < 4; ++h)
    bptr[h] = reinterpret_cast<const uint4*>(
        tail16 + (b * 256 + nt * 64 + h * 16 + r15) * 224);

  f32x4 acc[4][4] = {};
  #pragma unroll
  for (int ks = 0; ks < 7; ++ks) {
    int idx = ks * 4 + g8;
    half8 a[4], bb[4];
    #pragma unroll
    for (int g = 0; g < 4; ++g)
      a[g] = *reinterpret_cast<const half8*>(&Ps[(g * 16 + r15) * 232 + ks * 32 + g8 * 8]);
    #pragma unroll
    for (int h = 0; h < 4; ++h) bb[h] = __builtin_bit_cast(half8, bptr[h][idx]);
    #pragma unroll
    for (int g = 0; g < 4; ++g) {
      #pragma unroll
      for (int h = 0; h < 4; ++h)
        acc[g][h] = mfma16(a[g], bb[h], acc[g][h]);
    }
  }
  const float* Erow = E + o * 30;
  #pragma unroll
  for (int g = 0; g < 4; ++g) {
    #pragma unroll
    for (int q = 0; q < 4; ++q) {
      int m = mt * 64 + g * 16 + g8 * 4 + q;
      #pragma unroll
      for (int h = 0; h < 4; ++h) {
        int n = nt * 64 + h * 16 + r15;
        int dpos = n - m;
        dpos = (dpos < -15) ? -15 : (dpos > 14 ? 14 : dpos);
        out[((b * 12 + o) * 256 + m) * 256 + n] = acc[g][h][q] + Erow[dpos + 15];
      }
    }
  }
}

extern "C" void kernel_launch(void* const* d_in, const int* in_sizes, int n_in,
                              void* d_out, int out_size, void* d_ws, size_t ws_size,
                              hipStream_t stream) {
  (void)in_sizes; (void)n_in; (void)out_size; (void)ws_size;
  const float* wr = (const float*)d_in[0];
  const float* hw = (const float*)d_in[4];
  const float* hb = (const float*)d_in[5];
  const float* tw = (const float*)d_in[6];
  const float* tb = (const float*)d_in[7];
  const float* U  = (const float*)d_in[8];
  const float* se = (const float*)d_in[9];
  const float* W  = (const float*)d_in[10];
  const float* dw = (const float*)d_in[11];
  const float* db = (const float*)d_in[12];

  char* ws = (char*)d_ws;
  unsigned short* headp  = (unsigned short*)(ws + 0);        //   655,360  [1024][320]
  unsigned short* tail16 = (unsigned short*)(ws + 655360);   //   458,752  [1024][224]
  unsigned short* Gp     = (unsigned short*)(ws + 1114112);  //   307,200  [2400][64]
  unsigned short* DWhp   = (unsigned short*)(ws + 1421312);  //     7,680
  unsigned short* DWtp   = (unsigned short*)(ws + 1428992);  //     5,376
  float* biasH           = (float*)(ws + 1434368);           //        64
  float* biasT           = (float*)(ws + 1434432);           //        64
  float* E_ws            = (float*)(ws + 1434496);           //     1,440  -> end ~1.44 MB

  k1<<<1403, 64, 0, stream>>>(wr, hw, tw, hb, tb, U, W, dw, se,
                              headp, tail16, DWhp, DWtp, biasH, biasT, E_ws, Gp);
  k3<<<192, 256, 0, stream>>>(headp, tail16, Gp, DWhp, DWtp, biasH, biasT,
                              E_ws, db, (float*)d_out);
}